// Round 8
// baseline (584.558 us; speedup 1.0000x reference)
//
#include <hip/hip_runtime.h>
#include <hip/hip_bf16.h>

using bf16 = __hip_bfloat16;

#define NN 16384
#define NE 262144
#define ET (NE + NN)
#define NB 128
#define FEAT 78
#define HEADS 10
#define D1 780
#define OD 128
#define PL 1000
#define VOC 26
#define SLOPE 0.2f

// ---------------- CSR build ----------------
__global__ void k_hist(const int* __restrict__ ei, int* __restrict__ cnt){
    int e = blockIdx.x*256 + threadIdx.x;
    if (e >= ET) return;
    int dst = (e < NE) ? ei[NE + e] : (e - NE);
    atomicAdd(&cnt[dst], 1);
}

__global__ __launch_bounds__(1024) void k_scan(const int* __restrict__ cnt, int* __restrict__ off){
    __shared__ int ps[1024];
    int t = threadIdx.x;
    int loc[16]; int s = 0;
#pragma unroll
    for (int j = 0; j < 16; ++j){ loc[j] = cnt[t*16 + j]; s += loc[j]; }
    ps[t] = s; __syncthreads();
    for (int d = 1; d < 1024; d <<= 1){
        int v = (t >= d) ? ps[t - d] : 0;
        __syncthreads();
        ps[t] += v;
        __syncthreads();
    }
    int run = (t == 0) ? 0 : ps[t - 1];
#pragma unroll
    for (int j = 0; j < 16; ++j){ off[t*16 + j] = run; run += loc[j]; }
    if (t == 1023) off[NN] = run;
}

__global__ void k_fill(const int* __restrict__ ei, const int* __restrict__ off,
                       int* __restrict__ cur, int* __restrict__ csrc){
    int e = blockIdx.x*256 + threadIdx.x;
    if (e >= ET) return;
    int src, dst;
    if (e < NE){ src = ei[e]; dst = ei[NE + e]; } else { src = e - NE; dst = src; }
    int p = off[dst] + atomicAdd(&cur[dst], 1);
    csrc[p] = src;
}

// ---------------- GAT layer 1 (x-space) ----------------
__global__ __launch_bounds__(256) void k_va(const float* __restrict__ W1, const float* __restrict__ asw,
                                            const float* __restrict__ adw,
                                            float* __restrict__ vas, float* __restrict__ vad){
    __shared__ float sa[D1], sd[D1];
    int t = threadIdx.x;
    for (int i = t; i < D1; i += 256){ sa[i] = asw[i]; sd[i] = adw[i]; }
    __syncthreads();
    for (int idx = t; idx < D1; idx += 256){
        int h = idx / FEAT, k = idx % FEAT;
        const float* wr = W1 + (size_t)k*D1 + h*FEAT;
        float a = 0.f, d = 0.f;
        for (int j = 0; j < FEAT; ++j){ float w = wr[j]; a += w*sa[h*FEAT + j]; d += w*sd[h*FEAT + j]; }
        vas[idx] = a; vad[idx] = d;
    }
}

__global__ __launch_bounds__(256) void k_alpha1x(const float* __restrict__ x, const float* __restrict__ vas,
                                                 const float* __restrict__ vad,
                                                 float* __restrict__ as1, float* __restrict__ ad1){
    __shared__ float xs[64*79];
    __shared__ float va[D1], vd[D1];
    int n0 = blockIdx.x * 64, t = threadIdx.x;
    for (int i = t; i < D1; i += 256){ va[i] = vas[i]; vd[i] = vad[i]; }
    for (int i = t; i < 64*FEAT; i += 256){
        int n = i / FEAT, k = i % FEAT;
        xs[n*79 + k] = x[(size_t)n0*FEAT + i];
    }
    __syncthreads();
    for (int p = t; p < 64*HEADS; p += 256){
        int h = p >> 6, nl = p & 63;
        const float* xr = xs + nl*79;
        const float* pa = va + h*FEAT; const float* pd = vd + h*FEAT;
        float a = 0.f, d = 0.f;
        for (int k = 0; k < FEAT; ++k){ float xv = xr[k]; a += xv*pa[k]; d += xv*pd[k]; }
        as1[(size_t)(n0 + nl)*HEADS + h] = a;
        ad1[(size_t)(n0 + nl)*HEADS + h] = d;
    }
}

// per dst: lane j owns edge beg+j; wave reductions for softmax; shfl-broadcast agg
__global__ __launch_bounds__(64) void k_gat1x(const float* __restrict__ x, const float* __restrict__ as1,
                                              const float* __restrict__ ad1, const int* __restrict__ off,
                                              const int* __restrict__ csrc,
                                              float* __restrict__ agg){
    int dst = blockIdx.x, lane = threadIdx.x;
    int beg = off[dst], end = off[dst + 1];
    int deg = end - beg;
    float adh[HEADS];
#pragma unroll
    for (int h = 0; h < HEADS; ++h) adh[h] = ad1[(size_t)dst*HEADS + h];
    int s0 = 0;
    float p[HEADS], mx[HEADS];
#pragma unroll
    for (int h = 0; h < HEADS; ++h){ mx[h] = -1e30f; p[h] = 0.f; }
    if (lane < deg){
        s0 = csrc[beg + lane];
#pragma unroll
        for (int h = 0; h < HEADS; ++h){
            float v = as1[(size_t)s0*HEADS + h] + adh[h];
            v = v > 0.f ? v : SLOPE*v;
            p[h] = v; mx[h] = v;
        }
    }
    if (deg > 64){
        for (int e = beg + 64 + lane; e < end; e += 64){
            int s = csrc[e];
#pragma unroll
            for (int h = 0; h < HEADS; ++h){
                float v = as1[(size_t)s*HEADS + h] + adh[h];
                v = v > 0.f ? v : SLOPE*v;
                mx[h] = fmaxf(mx[h], v);
            }
        }
    }
#pragma unroll
    for (int h = 0; h < HEADS; ++h)
        for (int o = 32; o; o >>= 1) mx[h] = fmaxf(mx[h], __shfl_xor(mx[h], o));
    float sm[HEADS];
#pragma unroll
    for (int h = 0; h < HEADS; ++h) sm[h] = 0.f;
    if (lane < deg){
#pragma unroll
        for (int h = 0; h < HEADS; ++h){ p[h] = __expf(p[h] - mx[h]); sm[h] = p[h]; }
    }
    if (deg > 64){
        for (int e = beg + 64 + lane; e < end; e += 64){
            int s = csrc[e];
#pragma unroll
            for (int h = 0; h < HEADS; ++h){
                float v = as1[(size_t)s*HEADS + h] + adh[h];
                v = v > 0.f ? v : SLOPE*v;
                sm[h] += __expf(v - mx[h]);
            }
        }
    }
    float inv[HEADS];
#pragma unroll
    for (int h = 0; h < HEADS; ++h){
        for (int o = 32; o; o >>= 1) sm[h] += __shfl_xor(sm[h], o);
        inv[h] = 1.f/(sm[h] + 1e-16f);
        p[h] = (lane < deg) ? p[h]*inv[h] : 0.f;
    }
    float acc1[HEADS], acc2[HEADS];
#pragma unroll
    for (int h = 0; h < HEADS; ++h){ acc1[h] = 0.f; acc2[h] = 0.f; }
    int cnt0 = deg < 64 ? deg : 64;
    for (int q = 0; q < cnt0; ++q){
        int s = __shfl(s0, q);
        const float* xr = x + (size_t)s*FEAT;
        float xv1 = xr[lane];
        float xv2 = (lane < FEAT - 64) ? xr[64 + lane] : 0.f;
#pragma unroll
        for (int h = 0; h < HEADS; ++h){
            float al = __shfl(p[h], q);
            acc1[h] += al*xv1;
            acc2[h] += al*xv2;
        }
    }
    if (deg > 64){
        for (int base = beg + 64; base < end; base += 64){
            int cnt = min(64, end - base);
            int s1 = 0;
            float pp[HEADS];
#pragma unroll
            for (int h = 0; h < HEADS; ++h) pp[h] = 0.f;
            if (lane < cnt){
                s1 = csrc[base + lane];
#pragma unroll
                for (int h = 0; h < HEADS; ++h){
                    float v = as1[(size_t)s1*HEADS + h] + adh[h];
                    v = v > 0.f ? v : SLOPE*v;
                    pp[h] = __expf(v - mx[h])*inv[h];
                }
            }
            for (int q = 0; q < cnt; ++q){
                int s = __shfl(s1, q);
                const float* xr = x + (size_t)s*FEAT;
                float xv1 = xr[lane];
                float xv2 = (lane < FEAT - 64) ? xr[64 + lane] : 0.f;
#pragma unroll
                for (int h = 0; h < HEADS; ++h){
                    float al = __shfl(pp[h], q);
                    acc1[h] += al*xv1;
                    acc2[h] += al*xv2;
                }
            }
        }
    }
#pragma unroll
    for (int h = 0; h < HEADS; ++h)
        agg[(size_t)dst*D1 + h*FEAT + lane] = acc1[h];
    if (lane < FEAT - 64){
#pragma unroll
        for (int h = 0; h < HEADS; ++h)
            agg[(size_t)dst*D1 + h*FEAT + 64 + lane] = acc2[h];
    }
}

__global__ __launch_bounds__(320) void k_post1(const float* __restrict__ agg, const float* __restrict__ W1,
                                               const float* __restrict__ b1, float* __restrict__ h1){
    __shared__ __align__(16) float ags[8][800];
    int r0 = blockIdx.x * 8, t = threadIdx.x;
    for (int i = t; i < 8*D1; i += 320){
        int r = i / D1, c = i % D1, h = c / FEAT, j = c % FEAT;
        ags[r][h*80 + j] = agg[(size_t)(r0 + r)*D1 + c];
    }
    __syncthreads();
    if (t < 260){
        int h = t / 26, jj = (t % 26)*3;
        int cb = h*FEAT + jj;
        const float* wcol = W1 + cb;
        float acc[8][3];
#pragma unroll
        for (int r = 0; r < 8; ++r){ acc[r][0] = 0.f; acc[r][1] = 0.f; acc[r][2] = 0.f; }
        int k = 0;
        for (; k + 4 <= FEAT; k += 4){
            float4 a[8];
#pragma unroll
            for (int r = 0; r < 8; ++r) a[r] = *(const float4*)&ags[r][h*80 + k];
#pragma unroll
            for (int kk = 0; kk < 4; ++kk){
                const float* wr = wcol + (size_t)(k + kk)*D1;
                float w0 = wr[0], w1 = wr[1], w2 = wr[2];
#pragma unroll
                for (int r = 0; r < 8; ++r){
                    float av = ((const float*)&a[r])[kk];
                    acc[r][0] += av*w0; acc[r][1] += av*w1; acc[r][2] += av*w2;
                }
            }
        }
        for (; k < FEAT; ++k){
            const float* wr = wcol + (size_t)k*D1;
            float w0 = wr[0], w1 = wr[1], w2 = wr[2];
#pragma unroll
            for (int r = 0; r < 8; ++r){
                float av = ags[r][h*80 + k];
                acc[r][0] += av*w0; acc[r][1] += av*w1; acc[r][2] += av*w2;
            }
        }
        float bv0 = b1[cb], bv1 = b1[cb+1], bv2 = b1[cb+2];
#pragma unroll
        for (int r = 0; r < 8; ++r){
            float v0 = acc[r][0] + bv0, v1 = acc[r][1] + bv1, v2 = acc[r][2] + bv2;
            v0 = v0 > 0.f ? v0 : __expf(v0) - 1.f;
            v1 = v1 > 0.f ? v1 : __expf(v1) - 1.f;
            v2 = v2 > 0.f ? v2 : __expf(v2) - 1.f;
            size_t base = (size_t)(r0 + r)*D1 + cb;
            h1[base] = v0; h1[base+1] = v1; h1[base+2] = v2;
        }
    }
}

// ---------------- GAT layer 2 GEMM: 64x128 tile, K-split x4 ----------------
#define KC 39
#define KS 4
#define KSEG 195
__global__ __launch_bounds__(256) void k_gemm2(const float* __restrict__ h1, const float* __restrict__ W2,
                                               float* __restrict__ xlp){
    __shared__ __align__(16) float as[KC][68];
    __shared__ __align__(16) float ws[KC][128];
    int bid = blockIdx.x;
    int ks = bid & (KS - 1);
    int r0 = (bid >> 2) * 64;
    int t = threadIdx.x;
    int rg = t >> 5, jq = t & 31;
    float acc[8][4];
#pragma unroll
    for (int i = 0; i < 8; ++i)
#pragma unroll
        for (int j = 0; j < 4; ++j) acc[i][j] = 0.f;
    for (int kc = ks*KSEG; kc < ks*KSEG + KSEG; kc += KC){
        for (int i = t; i < 64*KC; i += 256){
            int r = i / KC, k = i % KC;
            as[k][r] = h1[(size_t)(r0 + r)*D1 + kc + k];
        }
        for (int i = t; i < KC*128; i += 256){
            int k = i >> 7, j = i & 127;
            ws[k][j] = W2[(size_t)(kc + k)*OD + j];
        }
        __syncthreads();
        for (int k = 0; k < KC; ++k){
            float4 a0 = *(const float4*)&as[k][rg*8];
            float4 a1 = *(const float4*)&as[k][rg*8 + 4];
            float4 w4 = *(const float4*)&ws[k][jq*4];
            float av[8] = {a0.x, a0.y, a0.z, a0.w, a1.x, a1.y, a1.z, a1.w};
            float wv[4] = {w4.x, w4.y, w4.z, w4.w};
#pragma unroll
            for (int i = 0; i < 8; ++i)
#pragma unroll
                for (int j = 0; j < 4; ++j) acc[i][j] += av[i]*wv[j];
        }
        __syncthreads();
    }
    float* dst = xlp + (size_t)ks*NN*OD;
#pragma unroll
    for (int i = 0; i < 8; ++i){
        float4 o4 = make_float4(acc[i][0], acc[i][1], acc[i][2], acc[i][3]);
        *(float4*)&dst[(size_t)(r0 + rg*8 + i)*OD + jq*4] = o4;
    }
}

// reduce 4 partials -> xl2, fused alpha2
__global__ __launch_bounds__(128) void k_red(const float* __restrict__ xlp,
                                             const float* __restrict__ s2w, const float* __restrict__ d2w,
                                             float* __restrict__ xl2,
                                             float* __restrict__ as2, float* __restrict__ ad2){
    const size_t Q = (size_t)NN*OD/4;
    int t = threadIdx.x;
    size_t fi = (size_t)blockIdx.x*128 + t;
    const float4* P = (const float4*)xlp;
    float4 a = P[fi], b = P[fi + Q], c = P[fi + 2*Q], d = P[fi + 3*Q];
    float4 v = make_float4(a.x+b.x+c.x+d.x, a.y+b.y+c.y+d.y,
                           a.z+b.z+c.z+d.z, a.w+b.w+c.w+d.w);
    ((float4*)xl2)[fi] = v;
    int cc = (t & 31)*4;
    float sa = v.x*s2w[cc] + v.y*s2w[cc+1] + v.z*s2w[cc+2] + v.w*s2w[cc+3];
    float sd = v.x*d2w[cc] + v.y*d2w[cc+1] + v.z*d2w[cc+2] + v.w*d2w[cc+3];
#pragma unroll
    for (int o = 16; o; o >>= 1){ sa += __shfl_xor(sa, o); sd += __shfl_xor(sd, o); }
    if ((t & 31) == 0){
        int n = blockIdx.x*4 + (t >> 5);
        as2[n] = sa; ad2[n] = sd;
    }
}

// per dst: lane-owned alpha + shfl broadcast
__global__ __launch_bounds__(64) void k_gat2(const float* __restrict__ xl2, const float* __restrict__ as2,
                                             const float* __restrict__ ad2, const int* __restrict__ off,
                                             const int* __restrict__ csrc, const float* __restrict__ b2,
                                             float* __restrict__ h2){
    int dst = blockIdx.x, lane = threadIdx.x;
    int beg = off[dst], end = off[dst + 1];
    int deg = end - beg;
    float ad = ad2[dst];
    int s0 = 0; float v0 = -1e30f;
    if (lane < deg){
        s0 = csrc[beg + lane];
        float v = as2[s0] + ad;
        v0 = v > 0.f ? v : SLOPE*v;
    }
    float m = v0;
    if (deg > 64){
        for (int e = beg + 64 + lane; e < end; e += 64){
            float v = as2[csrc[e]] + ad; v = v > 0.f ? v : SLOPE*v;
            m = fmaxf(m, v);
        }
    }
    for (int o = 32; o; o >>= 1) m = fmaxf(m, __shfl_xor(m, o));
    float pe = (lane < deg) ? __expf(v0 - m) : 0.f;
    float sm = pe;
    if (deg > 64){
        for (int e = beg + 64 + lane; e < end; e += 64){
            float v = as2[csrc[e]] + ad; v = v > 0.f ? v : SLOPE*v;
            sm += __expf(v - m);
        }
    }
    for (int o = 32; o; o >>= 1) sm += __shfl_xor(sm, o);
    float inv = 1.f / (sm + 1e-16f);
    float p = pe * inv;
    float a0 = 0.f, a1 = 0.f;
    int cnt0 = deg < 64 ? deg : 64;
    for (int q = 0; q < cnt0; ++q){
        int s = __shfl(s0, q);
        float al = __shfl(p, q);
        a0 += al * xl2[(size_t)s*OD + lane];
        a1 += al * xl2[(size_t)s*OD + 64 + lane];
    }
    if (deg > 64){
        for (int base = beg + 64; base < end; base += 64){
            int cnt = min(64, end - base);
            int s1 = 0; float pp = 0.f;
            if (lane < cnt){
                s1 = csrc[base + lane];
                float v = as2[s1] + ad; v = v > 0.f ? v : SLOPE*v;
                pp = __expf(v - m) * inv;
            }
            for (int q = 0; q < cnt; ++q){
                int s = __shfl(s1, q);
                float al = __shfl(pp, q);
                a0 += al * xl2[(size_t)s*OD + lane];
                a1 += al * xl2[(size_t)s*OD + 64 + lane];
            }
        }
    }
    float o0 = a0 + b2[lane];      o0 = o0 > 0.f ? o0 : 0.f;
    float o1 = a1 + b2[64 + lane]; o1 = o1 > 0.f ? o1 : 0.f;
    h2[(size_t)dst*OD + lane] = o0;
    h2[(size_t)dst*OD + 64 + lane] = o1;
}

// ---------------- pooling + graph FC (fused) ----------------
__global__ __launch_bounds__(128) void k_poolfc(const float* __restrict__ h2, const int* __restrict__ batch,
                                                const float* __restrict__ w, const float* __restrict__ bias,
                                                float* __restrict__ gfc){
    __shared__ float row[OD];
    int b = blockIdx.x, t = threadIdx.x;
    int lo = 0, hi = NN;
    while (lo < hi){ int mid = (lo + hi) >> 1; if (batch[mid] < b) lo = mid + 1; else hi = mid; }
    int s0 = lo;
    lo = s0; hi = NN;
    while (lo < hi){ int mid = (lo + hi) >> 1; if (batch[mid] < b + 1) lo = mid + 1; else hi = mid; }
    int s1 = lo;
    float mx = 0.f;
    for (int n = s0; n < s1; ++n) mx = fmaxf(mx, h2[(size_t)n*OD + t]);
    row[t] = mx;
    __syncthreads();
    float acc = 0.f;
    for (int k = 0; k < OD; ++k) acc += row[k] * w[k*OD + t];
    acc += bias[t];
    gfc[b*OD + t] = acc > 0.f ? acc : 0.f;
}

// ---------------- protein branch ----------------
// one-time transpose: wt[i][o*8+k] = convw[o][i][k]  (coalesced A-build loads)
__global__ __launch_bounds__(256) void k_wt(const float* __restrict__ convw, float* __restrict__ wt){
    int idx = blockIdx.x*256 + threadIdx.x;
    int i = idx >> 8, ok = idx & 255;
    wt[idx] = convw[(size_t)(ok >> 3)*PL*8 + (size_t)i*8 + (ok & 7)];
}

// A-partials per (b, seg of 250 positions): fire-and-forget LDS adds, no RMW chain
__global__ __launch_bounds__(256) void k_abuild(const int* __restrict__ target, const float* __restrict__ wt,
                                                float* __restrict__ Ag){
    __shared__ float A[VOC][256];
    __shared__ int tss[256];
    int b = blockIdx.x >> 2, seg = blockIdx.x & 3;
    int t = threadIdx.x;
#pragma unroll
    for (int v = 0; v < VOC; ++v) A[v][t] = 0.f;
    if (t < 250) tss[t] = target[b*PL + seg*250 + t];
    __syncthreads();
    const float* wtb = wt + (size_t)(seg*250)*256 + t;
#pragma unroll 10
    for (int i = 0; i < 250; ++i){
        float w = wtb[(size_t)i*256];
        atomicAdd(&A[tss[i]][t], w);   // ds_add_f32, fire-and-forget; cell owned by thread t
    }
    __syncthreads();
    float* Ao = Ag + (size_t)blockIdx.x*VOC*256 + t;
#pragma unroll
    for (int v = 0; v < VOC; ++v) Ao[(size_t)v*256] = A[v][t];
}

// c[b][o][p] = relu( sum_v sum_k (Σ_seg A)[v][o*8+k]*emb[v][p+k] + cb[o] ), block=(b,half)
__global__ __launch_bounds__(256) void k_conv(const float* __restrict__ Ag, const float* __restrict__ emb,
                                              const float* __restrict__ convb, float* __restrict__ cbuf){
    __shared__ float As[VOC][128];
    __shared__ float embs[VOC*128 + 16];
    int b = blockIdx.x >> 1, half = blockIdx.x & 1;
    int t = threadIdx.x;
    for (int i = t; i < VOC*128; i += 256){
        int v = i >> 7, c = i & 127;
        float s = 0.f;
#pragma unroll
        for (int seg = 0; seg < 4; ++seg)
            s += Ag[((size_t)(b*4 + seg)*VOC + v)*256 + half*128 + c];
        As[v][c] = s;
        embs[i] = emb[i];
    }
    if (t < 16) embs[VOC*128 + t] = 0.f;
    __syncthreads();
    int o_l = t >> 4, pg = t & 15, p0 = pg * 8;
    float accp[8];
#pragma unroll
    for (int i = 0; i < 8; ++i) accp[i] = 0.f;
    for (int v = 0; v < VOC; ++v){
        float w[15];
        const float* er = embs + v*128 + p0;
#pragma unroll
        for (int i = 0; i < 15; ++i) w[i] = er[i];
#pragma unroll
        for (int k2 = 0; k2 < 8; ++k2){
            float a = As[v][o_l*8 + k2];
#pragma unroll
            for (int j = 0; j < 8; ++j) accp[j] += a * w[j + k2];
        }
    }
    float cbv = convb[half*16 + o_l];
#pragma unroll
    for (int j = 0; j < 8; ++j){
        int p = p0 + j;
        if (p < 121){
            float v2 = accp[j] + cbv;
            cbuf[(size_t)b*3872 + (half*16 + o_l)*121 + p] = v2 > 0.f ? v2 : 0.f;
        }
    }
}

__global__ __launch_bounds__(256) void k_xt(const float* __restrict__ cbuf, const float* __restrict__ fxw,
                                            float* __restrict__ xtp){
    __shared__ float csh[16][242];
    int kt = blockIdx.x >> 3, bt = blockIdx.x & 7;
    int t = threadIdx.x;
    for (int i = t; i < 16*242; i += 256){
        int bb = i / 242, kk = i % 242;
        csh[bb][kk] = cbuf[(size_t)(bt*16 + bb)*3872 + kt*242 + kk];
    }
    __syncthreads();
    int j = t & 127, bh = t >> 7;
    float acc[8];
#pragma unroll
    for (int i = 0; i < 8; ++i) acc[i] = 0.f;
    for (int kk = 0; kk < 242; ++kk){
        float w = fxw[(size_t)(kt*242 + kk)*128 + j];
#pragma unroll
        for (int bb = 0; bb < 8; ++bb) acc[bb] += csh[bh*8 + bb][kk] * w;
    }
#pragma unroll
    for (int bb = 0; bb < 8; ++bb)
        xtp[(size_t)kt*NB*128 + (size_t)(bt*16 + bh*8 + bb)*128 + j] = acc[bb];
}

// ---------------- fused head ----------------
__global__ __launch_bounds__(256) void k_fc1(const float* __restrict__ gfc, const float* __restrict__ xtp,
                                             const float* __restrict__ fxb,
                                             const float* __restrict__ w, const float* __restrict__ bias,
                                             float* __restrict__ out){
    __shared__ float xc[256];
    int b = blockIdx.x, t = threadIdx.x;
    if (t < 128) xc[t] = gfc[b*OD + t];
    else {
        int j = t - 128;
        float s = fxb[j];
#pragma unroll
        for (int kt = 0; kt < 16; ++kt) s += xtp[(size_t)kt*NB*128 + (size_t)b*128 + j];
        xc[t] = s;
    }
    __syncthreads();
#pragma unroll
    for (int rep = 0; rep < 4; ++rep){
        int j = t + rep*256;
        float acc = 0.f;
        for (int k = 0; k < 256; ++k) acc += xc[k] * w[(size_t)k*1024 + j];
        acc += bias[j];
        out[b*1024 + j] = acc > 0.f ? acc : 0.f;
    }
}

__global__ __launch_bounds__(256) void k_fc2o(const float* __restrict__ in, const float* __restrict__ w,
                                              const float* __restrict__ bias, const float* __restrict__ ow,
                                              const float* __restrict__ ob, float* __restrict__ out){
    __shared__ float row[1024];
    __shared__ float s2[256];
    int b = blockIdx.x, t = threadIdx.x;
    for (int i = t; i < 1024; i += 256) row[i] = in[b*1024 + i];
    __syncthreads();
    float acc = 0.f;
    for (int k = 0; k < 1024; ++k) acc += row[k] * w[(size_t)k*256 + t];
    acc += bias[t];
    acc = acc > 0.f ? acc : 0.f;
    s2[t] = acc * ow[t];
    __syncthreads();
    if (t < 64){
        float a = s2[t] + s2[t + 64] + s2[t + 128] + s2[t + 192];
#pragma unroll
        for (int o = 32; o; o >>= 1) a += __shfl_xor(a, o);
        if (t == 0) out[b] = a + ob[0];
    }
}

extern "C" void kernel_launch(void* const* d_in, const int* in_sizes, int n_in,
                              void* d_out, int out_size, void* d_ws, size_t ws_size,
                              hipStream_t stream){
    const float* x    = (const float*)d_in[0];
    const int*  ei    = (const int*)d_in[1];
    const int*  batch = (const int*)d_in[2];
    const int*  target= (const int*)d_in[3];
    const float* W1   = (const float*)d_in[4];
    const float* as1w = (const float*)d_in[5];
    const float* ad1w = (const float*)d_in[6];
    const float* b1   = (const float*)d_in[7];
    const float* W2   = (const float*)d_in[8];
    const float* as2w = (const float*)d_in[9];
    const float* ad2w = (const float*)d_in[10];
    const float* b2   = (const float*)d_in[11];
    const float* fgw  = (const float*)d_in[12];
    const float* fgb  = (const float*)d_in[13];
    const float* emb  = (const float*)d_in[14];
    const float* cw   = (const float*)d_in[15];
    const float* cb   = (const float*)d_in[16];
    const float* fxw  = (const float*)d_in[17];
    const float* fxb  = (const float*)d_in[18];
    const float* f1w  = (const float*)d_in[19];
    const float* f1b  = (const float*)d_in[20];
    const float* f2w  = (const float*)d_in[21];
    const float* f2b  = (const float*)d_in[22];
    const float* ow   = (const float*)d_in[23];
    const float* ob   = (const float*)d_in[24];

    float* f = (float*)d_ws;
    size_t o = 0;
    float* agg = f + o; o += (size_t)NN*D1;     // reused as xlp (4*NN*OD <= NN*D1)
    float* h1  = f + o; o += (size_t)NN*D1;     // reused as Ag after k_gemm2 (3.4M <= 12.8M)
    float* as1 = f + o; o += (size_t)NN*HEADS;
    float* ad1 = f + o; o += (size_t)NN*HEADS;
    float* xl2 = f + o; o += (size_t)NN*OD;
    float* h2  = f + o; o += (size_t)NN*OD;
    float* as2 = f + o; o += NN;
    float* ad2 = f + o; o += NN;
    float* gfc = f + o; o += NB*OD;
    float* hf1 = f + o; o += NB*1024;
    float* vas = f + o; o += D1;
    float* vad = f + o; o += D1;
    float* wt  = f + o; o += (size_t)PL*256;
    float* cbuf= f + o; o += (size_t)NB*3872;
    float* xtp = f + o; o += (size_t)16*NB*128;
    int* cnt   = (int*)(f + o); o += NN;
    int* off   = (int*)(f + o); o += NN + 1;
    int* csrc  = (int*)(f + o); o += ET;
    float* xlp = agg;   // agg dead after k_post1
    float* Ag  = h1;    // h1 dead after k_gemm2; abuild launches after k_poolfc
    (void)ws_size; (void)in_sizes; (void)n_in; (void)out_size;

    // CSR by destination
    hipMemsetAsync(cnt, 0, NN*sizeof(int), stream);
    k_hist<<<(ET + 255)/256, 256, 0, stream>>>(ei, cnt);
    k_scan<<<1, 1024, 0, stream>>>(cnt, off);
    hipMemsetAsync(cnt, 0, NN*sizeof(int), stream);
    k_fill<<<(ET + 255)/256, 256, 0, stream>>>(ei, off, cnt, csrc);

    // GAT layer 1 in x-space
    k_va<<<1, 256, 0, stream>>>(W1, as1w, ad1w, vas, vad);
    k_alpha1x<<<NN/64, 256, 0, stream>>>(x, vas, vad, as1, ad1);
    k_gat1x<<<NN, 64, 0, stream>>>(x, as1, ad1, off, csrc, agg);
    k_post1<<<NN/8, 320, 0, stream>>>(agg, W1, b1, h1);

    // GAT layer 2 (K-split GEMM + fused reduce/alpha2)
    k_gemm2<<<(NN/64)*KS, 256, 0, stream>>>(h1, W2, xlp);
    k_red<<<NN/4, 128, 0, stream>>>(xlp, as2w, ad2w, xl2, as2, ad2);
    k_gat2<<<NN, 64, 0, stream>>>(xl2, as2, ad2, off, csrc, b2, h2);

    // pooling + graph fc (fused)
    k_poolfc<<<NB, 128, 0, stream>>>(h2, batch, fgw, fgb, gfc);

    // protein branch
    k_wt<<<1000, 256, 0, stream>>>(cw, wt);
    k_abuild<<<NB*4, 256, 0, stream>>>(target, wt, Ag);
    k_conv<<<NB*2, 256, 0, stream>>>(Ag, emb, cb, cbuf);
    k_xt<<<128, 256, 0, stream>>>(cbuf, fxw, xtp);

    // head
    k_fc1<<<NB, 256, 0, stream>>>(gfc, xtp, fxb, f1w, f1b, hf1);
    k_fc2o<<<NB, 256, 0, stream>>>(hf1, f2w, f2b, ow, ob, (float*)d_out);
}

// Round 9
// 491.793 us; speedup vs baseline: 1.1886x; 1.1886x over previous
//
#include <hip/hip_runtime.h>
#include <hip/hip_bf16.h>

using bf16 = __hip_bfloat16;

#define NN 16384
#define NE 262144
#define ET (NE + NN)
#define NB 128
#define FEAT 78
#define HEADS 10
#define D1 780
#define OD 128
#define PL 1000
#define VOC 26
#define SLOPE 0.2f

// ---------------- CSR build ----------------
__global__ void k_hist(const int* __restrict__ ei, int* __restrict__ cnt){
    int e = blockIdx.x*256 + threadIdx.x;
    if (e >= ET) return;
    int dst = (e < NE) ? ei[NE + e] : (e - NE);
    atomicAdd(&cnt[dst], 1);
}

__global__ __launch_bounds__(1024) void k_scan(const int* __restrict__ cnt, int* __restrict__ off){
    __shared__ int ps[1024];
    int t = threadIdx.x;
    int loc[16]; int s = 0;
#pragma unroll
    for (int j = 0; j < 16; ++j){ loc[j] = cnt[t*16 + j]; s += loc[j]; }
    ps[t] = s; __syncthreads();
    for (int d = 1; d < 1024; d <<= 1){
        int v = (t >= d) ? ps[t - d] : 0;
        __syncthreads();
        ps[t] += v;
        __syncthreads();
    }
    int run = (t == 0) ? 0 : ps[t - 1];
#pragma unroll
    for (int j = 0; j < 16; ++j){ off[t*16 + j] = run; run += loc[j]; }
    if (t == 1023) off[NN] = run;
}

__global__ void k_fill(const int* __restrict__ ei, const int* __restrict__ off,
                       int* __restrict__ cur, int* __restrict__ csrc){
    int e = blockIdx.x*256 + threadIdx.x;
    if (e >= ET) return;
    int src, dst;
    if (e < NE){ src = ei[e]; dst = ei[NE + e]; } else { src = e - NE; dst = src; }
    int p = off[dst] + atomicAdd(&cur[dst], 1);
    csrc[p] = src;
}

// ---------------- GAT layer 1 (x-space) ----------------
__global__ __launch_bounds__(256) void k_va(const float* __restrict__ W1, const float* __restrict__ asw,
                                            const float* __restrict__ adw,
                                            float* __restrict__ vas, float* __restrict__ vad){
    __shared__ float sa[D1], sd[D1];
    int t = threadIdx.x;
    for (int i = t; i < D1; i += 256){ sa[i] = asw[i]; sd[i] = adw[i]; }
    __syncthreads();
    for (int idx = t; idx < D1; idx += 256){
        int h = idx / FEAT, k = idx % FEAT;
        const float* wr = W1 + (size_t)k*D1 + h*FEAT;
        float a = 0.f, d = 0.f;
        for (int j = 0; j < FEAT; ++j){ float w = wr[j]; a += w*sa[h*FEAT + j]; d += w*sd[h*FEAT + j]; }
        vas[idx] = a; vad[idx] = d;
    }
}

__global__ __launch_bounds__(256) void k_alpha1x(const float* __restrict__ x, const float* __restrict__ vas,
                                                 const float* __restrict__ vad,
                                                 float* __restrict__ as1, float* __restrict__ ad1){
    __shared__ float xs[64*79];
    __shared__ float va[D1], vd[D1];
    int n0 = blockIdx.x * 64, t = threadIdx.x;
    for (int i = t; i < D1; i += 256){ va[i] = vas[i]; vd[i] = vad[i]; }
    for (int i = t; i < 64*FEAT; i += 256){
        int n = i / FEAT, k = i % FEAT;
        xs[n*79 + k] = x[(size_t)n0*FEAT + i];
    }
    __syncthreads();
    for (int p = t; p < 64*HEADS; p += 256){
        int h = p >> 6, nl = p & 63;
        const float* xr = xs + nl*79;
        const float* pa = va + h*FEAT; const float* pd = vd + h*FEAT;
        float a = 0.f, d = 0.f;
        for (int k = 0; k < FEAT; ++k){ float xv = xr[k]; a += xv*pa[k]; d += xv*pd[k]; }
        as1[(size_t)(n0 + nl)*HEADS + h] = a;
        ad1[(size_t)(n0 + nl)*HEADS + h] = d;
    }
}

// per dst: lane j owns edge beg+j; wave reductions for softmax; shfl-broadcast agg
__global__ __launch_bounds__(64) void k_gat1x(const float* __restrict__ x, const float* __restrict__ as1,
                                              const float* __restrict__ ad1, const int* __restrict__ off,
                                              const int* __restrict__ csrc,
                                              float* __restrict__ agg){
    int dst = blockIdx.x, lane = threadIdx.x;
    int beg = off[dst], end = off[dst + 1];
    int deg = end - beg;
    float adh[HEADS];
#pragma unroll
    for (int h = 0; h < HEADS; ++h) adh[h] = ad1[(size_t)dst*HEADS + h];
    int s0 = 0;
    float p[HEADS], mx[HEADS];
#pragma unroll
    for (int h = 0; h < HEADS; ++h){ mx[h] = -1e30f; p[h] = 0.f; }
    if (lane < deg){
        s0 = csrc[beg + lane];
#pragma unroll
        for (int h = 0; h < HEADS; ++h){
            float v = as1[(size_t)s0*HEADS + h] + adh[h];
            v = v > 0.f ? v : SLOPE*v;
            p[h] = v; mx[h] = v;
        }
    }
    if (deg > 64){
        for (int e = beg + 64 + lane; e < end; e += 64){
            int s = csrc[e];
#pragma unroll
            for (int h = 0; h < HEADS; ++h){
                float v = as1[(size_t)s*HEADS + h] + adh[h];
                v = v > 0.f ? v : SLOPE*v;
                mx[h] = fmaxf(mx[h], v);
            }
        }
    }
#pragma unroll
    for (int h = 0; h < HEADS; ++h)
        for (int o = 32; o; o >>= 1) mx[h] = fmaxf(mx[h], __shfl_xor(mx[h], o));
    float sm[HEADS];
#pragma unroll
    for (int h = 0; h < HEADS; ++h) sm[h] = 0.f;
    if (lane < deg){
#pragma unroll
        for (int h = 0; h < HEADS; ++h){ p[h] = __expf(p[h] - mx[h]); sm[h] = p[h]; }
    }
    if (deg > 64){
        for (int e = beg + 64 + lane; e < end; e += 64){
            int s = csrc[e];
#pragma unroll
            for (int h = 0; h < HEADS; ++h){
                float v = as1[(size_t)s*HEADS + h] + adh[h];
                v = v > 0.f ? v : SLOPE*v;
                sm[h] += __expf(v - mx[h]);
            }
        }
    }
    float inv[HEADS];
#pragma unroll
    for (int h = 0; h < HEADS; ++h){
        for (int o = 32; o; o >>= 1) sm[h] += __shfl_xor(sm[h], o);
        inv[h] = 1.f/(sm[h] + 1e-16f);
        p[h] = (lane < deg) ? p[h]*inv[h] : 0.f;
    }
    float acc1[HEADS], acc2[HEADS];
#pragma unroll
    for (int h = 0; h < HEADS; ++h){ acc1[h] = 0.f; acc2[h] = 0.f; }
    int cnt0 = deg < 64 ? deg : 64;
    for (int q = 0; q < cnt0; ++q){
        int s = __shfl(s0, q);
        const float* xr = x + (size_t)s*FEAT;
        float xv1 = xr[lane];
        float xv2 = (lane < FEAT - 64) ? xr[64 + lane] : 0.f;
#pragma unroll
        for (int h = 0; h < HEADS; ++h){
            float al = __shfl(p[h], q);
            acc1[h] += al*xv1;
            acc2[h] += al*xv2;
        }
    }
    if (deg > 64){
        for (int base = beg + 64; base < end; base += 64){
            int cnt = min(64, end - base);
            int s1 = 0;
            float pp[HEADS];
#pragma unroll
            for (int h = 0; h < HEADS; ++h) pp[h] = 0.f;
            if (lane < cnt){
                s1 = csrc[base + lane];
#pragma unroll
                for (int h = 0; h < HEADS; ++h){
                    float v = as1[(size_t)s1*HEADS + h] + adh[h];
                    v = v > 0.f ? v : SLOPE*v;
                    pp[h] = __expf(v - mx[h])*inv[h];
                }
            }
            for (int q = 0; q < cnt; ++q){
                int s = __shfl(s1, q);
                const float* xr = x + (size_t)s*FEAT;
                float xv1 = xr[lane];
                float xv2 = (lane < FEAT - 64) ? xr[64 + lane] : 0.f;
#pragma unroll
                for (int h = 0; h < HEADS; ++h){
                    float al = __shfl(pp[h], q);
                    acc1[h] += al*xv1;
                    acc2[h] += al*xv2;
                }
            }
        }
    }
#pragma unroll
    for (int h = 0; h < HEADS; ++h)
        agg[(size_t)dst*D1 + h*FEAT + lane] = acc1[h];
    if (lane < FEAT - 64){
#pragma unroll
        for (int h = 0; h < HEADS; ++h)
            agg[(size_t)dst*D1 + h*FEAT + 64 + lane] = acc2[h];
    }
}

__global__ __launch_bounds__(320) void k_post1(const float* __restrict__ agg, const float* __restrict__ W1,
                                               const float* __restrict__ b1, float* __restrict__ h1){
    __shared__ __align__(16) float ags[8][800];
    int r0 = blockIdx.x * 8, t = threadIdx.x;
    for (int i = t; i < 8*D1; i += 320){
        int r = i / D1, c = i % D1, h = c / FEAT, j = c % FEAT;
        ags[r][h*80 + j] = agg[(size_t)(r0 + r)*D1 + c];
    }
    __syncthreads();
    if (t < 260){
        int h = t / 26, jj = (t % 26)*3;
        int cb = h*FEAT + jj;
        const float* wcol = W1 + cb;
        float acc[8][3];
#pragma unroll
        for (int r = 0; r < 8; ++r){ acc[r][0] = 0.f; acc[r][1] = 0.f; acc[r][2] = 0.f; }
        int k = 0;
        for (; k + 4 <= FEAT; k += 4){
            float4 a[8];
#pragma unroll
            for (int r = 0; r < 8; ++r) a[r] = *(const float4*)&ags[r][h*80 + k];
#pragma unroll
            for (int kk = 0; kk < 4; ++kk){
                const float* wr = wcol + (size_t)(k + kk)*D1;
                float w0 = wr[0], w1 = wr[1], w2 = wr[2];
#pragma unroll
                for (int r = 0; r < 8; ++r){
                    float av = ((const float*)&a[r])[kk];
                    acc[r][0] += av*w0; acc[r][1] += av*w1; acc[r][2] += av*w2;
                }
            }
        }
        for (; k < FEAT; ++k){
            const float* wr = wcol + (size_t)k*D1;
            float w0 = wr[0], w1 = wr[1], w2 = wr[2];
#pragma unroll
            for (int r = 0; r < 8; ++r){
                float av = ags[r][h*80 + k];
                acc[r][0] += av*w0; acc[r][1] += av*w1; acc[r][2] += av*w2;
            }
        }
        float bv0 = b1[cb], bv1 = b1[cb+1], bv2 = b1[cb+2];
#pragma unroll
        for (int r = 0; r < 8; ++r){
            float v0 = acc[r][0] + bv0, v1 = acc[r][1] + bv1, v2 = acc[r][2] + bv2;
            v0 = v0 > 0.f ? v0 : __expf(v0) - 1.f;
            v1 = v1 > 0.f ? v1 : __expf(v1) - 1.f;
            v2 = v2 > 0.f ? v2 : __expf(v2) - 1.f;
            size_t base = (size_t)(r0 + r)*D1 + cb;
            h1[base] = v0; h1[base+1] = v1; h1[base+2] = v2;
        }
    }
}

// ---------------- GAT layer 2 GEMM: 64x128 tile, K-split x4 ----------------
#define KC 39
#define KS 4
#define KSEG 195
__global__ __launch_bounds__(256) void k_gemm2(const float* __restrict__ h1, const float* __restrict__ W2,
                                               float* __restrict__ xlp){
    __shared__ __align__(16) float as[KC][68];
    __shared__ __align__(16) float ws[KC][128];
    int bid = blockIdx.x;
    int ks = bid & (KS - 1);
    int r0 = (bid >> 2) * 64;
    int t = threadIdx.x;
    int rg = t >> 5, jq = t & 31;
    float acc[8][4];
#pragma unroll
    for (int i = 0; i < 8; ++i)
#pragma unroll
        for (int j = 0; j < 4; ++j) acc[i][j] = 0.f;
    for (int kc = ks*KSEG; kc < ks*KSEG + KSEG; kc += KC){
        for (int i = t; i < 64*KC; i += 256){
            int r = i / KC, k = i % KC;
            as[k][r] = h1[(size_t)(r0 + r)*D1 + kc + k];
        }
        for (int i = t; i < KC*128; i += 256){
            int k = i >> 7, j = i & 127;
            ws[k][j] = W2[(size_t)(kc + k)*OD + j];
        }
        __syncthreads();
        for (int k = 0; k < KC; ++k){
            float4 a0 = *(const float4*)&as[k][rg*8];
            float4 a1 = *(const float4*)&as[k][rg*8 + 4];
            float4 w4 = *(const float4*)&ws[k][jq*4];
            float av[8] = {a0.x, a0.y, a0.z, a0.w, a1.x, a1.y, a1.z, a1.w};
            float wv[4] = {w4.x, w4.y, w4.z, w4.w};
#pragma unroll
            for (int i = 0; i < 8; ++i)
#pragma unroll
                for (int j = 0; j < 4; ++j) acc[i][j] += av[i]*wv[j];
        }
        __syncthreads();
    }
    float* dst = xlp + (size_t)ks*NN*OD;
#pragma unroll
    for (int i = 0; i < 8; ++i){
        float4 o4 = make_float4(acc[i][0], acc[i][1], acc[i][2], acc[i][3]);
        *(float4*)&dst[(size_t)(r0 + rg*8 + i)*OD + jq*4] = o4;
    }
}

// reduce 4 partials -> xl2, fused alpha2
__global__ __launch_bounds__(128) void k_red(const float* __restrict__ xlp,
                                             const float* __restrict__ s2w, const float* __restrict__ d2w,
                                             float* __restrict__ xl2,
                                             float* __restrict__ as2, float* __restrict__ ad2){
    const size_t Q = (size_t)NN*OD/4;
    int t = threadIdx.x;
    size_t fi = (size_t)blockIdx.x*128 + t;
    const float4* P = (const float4*)xlp;
    float4 a = P[fi], b = P[fi + Q], c = P[fi + 2*Q], d = P[fi + 3*Q];
    float4 v = make_float4(a.x+b.x+c.x+d.x, a.y+b.y+c.y+d.y,
                           a.z+b.z+c.z+d.z, a.w+b.w+c.w+d.w);
    ((float4*)xl2)[fi] = v;
    int cc = (t & 31)*4;
    float sa = v.x*s2w[cc] + v.y*s2w[cc+1] + v.z*s2w[cc+2] + v.w*s2w[cc+3];
    float sd = v.x*d2w[cc] + v.y*d2w[cc+1] + v.z*d2w[cc+2] + v.w*d2w[cc+3];
#pragma unroll
    for (int o = 16; o; o >>= 1){ sa += __shfl_xor(sa, o); sd += __shfl_xor(sd, o); }
    if ((t & 31) == 0){
        int n = blockIdx.x*4 + (t >> 5);
        as2[n] = sa; ad2[n] = sd;
    }
}

// per dst: lane-owned alpha + shfl broadcast
__global__ __launch_bounds__(64) void k_gat2(const float* __restrict__ xl2, const float* __restrict__ as2,
                                             const float* __restrict__ ad2, const int* __restrict__ off,
                                             const int* __restrict__ csrc, const float* __restrict__ b2,
                                             float* __restrict__ h2){
    int dst = blockIdx.x, lane = threadIdx.x;
    int beg = off[dst], end = off[dst + 1];
    int deg = end - beg;
    float ad = ad2[dst];
    int s0 = 0; float v0 = -1e30f;
    if (lane < deg){
        s0 = csrc[beg + lane];
        float v = as2[s0] + ad;
        v0 = v > 0.f ? v : SLOPE*v;
    }
    float m = v0;
    if (deg > 64){
        for (int e = beg + 64 + lane; e < end; e += 64){
            float v = as2[csrc[e]] + ad; v = v > 0.f ? v : SLOPE*v;
            m = fmaxf(m, v);
        }
    }
    for (int o = 32; o; o >>= 1) m = fmaxf(m, __shfl_xor(m, o));
    float pe = (lane < deg) ? __expf(v0 - m) : 0.f;
    float sm = pe;
    if (deg > 64){
        for (int e = beg + 64 + lane; e < end; e += 64){
            float v = as2[csrc[e]] + ad; v = v > 0.f ? v : SLOPE*v;
            sm += __expf(v - m);
        }
    }
    for (int o = 32; o; o >>= 1) sm += __shfl_xor(sm, o);
    float inv = 1.f / (sm + 1e-16f);
    float p = pe * inv;
    float a0 = 0.f, a1 = 0.f;
    int cnt0 = deg < 64 ? deg : 64;
    for (int q = 0; q < cnt0; ++q){
        int s = __shfl(s0, q);
        float al = __shfl(p, q);
        a0 += al * xl2[(size_t)s*OD + lane];
        a1 += al * xl2[(size_t)s*OD + 64 + lane];
    }
    if (deg > 64){
        for (int base = beg + 64; base < end; base += 64){
            int cnt = min(64, end - base);
            int s1 = 0; float pp = 0.f;
            if (lane < cnt){
                s1 = csrc[base + lane];
                float v = as2[s1] + ad; v = v > 0.f ? v : SLOPE*v;
                pp = __expf(v - m) * inv;
            }
            for (int q = 0; q < cnt; ++q){
                int s = __shfl(s1, q);
                float al = __shfl(pp, q);
                a0 += al * xl2[(size_t)s*OD + lane];
                a1 += al * xl2[(size_t)s*OD + 64 + lane];
            }
        }
    }
    float o0 = a0 + b2[lane];      o0 = o0 > 0.f ? o0 : 0.f;
    float o1 = a1 + b2[64 + lane]; o1 = o1 > 0.f ? o1 : 0.f;
    h2[(size_t)dst*OD + lane] = o0;
    h2[(size_t)dst*OD + 64 + lane] = o1;
}

// ---------------- pooling + graph FC (fused) ----------------
__global__ __launch_bounds__(128) void k_poolfc(const float* __restrict__ h2, const int* __restrict__ batch,
                                                const float* __restrict__ w, const float* __restrict__ bias,
                                                float* __restrict__ gfc){
    __shared__ float row[OD];
    int b = blockIdx.x, t = threadIdx.x;
    int lo = 0, hi = NN;
    while (lo < hi){ int mid = (lo + hi) >> 1; if (batch[mid] < b) lo = mid + 1; else hi = mid; }
    int s0 = lo;
    lo = s0; hi = NN;
    while (lo < hi){ int mid = (lo + hi) >> 1; if (batch[mid] < b + 1) lo = mid + 1; else hi = mid; }
    int s1 = lo;
    float mx = 0.f;
    for (int n = s0; n < s1; ++n) mx = fmaxf(mx, h2[(size_t)n*OD + t]);
    row[t] = mx;
    __syncthreads();
    float acc = 0.f;
    for (int k = 0; k < OD; ++k) acc += row[k] * w[k*OD + t];
    acc += bias[t];
    gfc[b*OD + t] = acc > 0.f ? acc : 0.f;
}

// ---------------- protein branch ----------------
// one-time transpose: wt[i][o*8+k] = convw[o][i][k]  (coalesced A-build loads)
__global__ __launch_bounds__(256) void k_wt(const float* __restrict__ convw, float* __restrict__ wt){
    int idx = blockIdx.x*256 + threadIdx.x;
    int i = idx >> 8, ok = idx & 255;
    wt[idx] = convw[(size_t)(ok >> 3)*PL*8 + (size_t)i*8 + (ok & 7)];
}

// A-partials per (b, seg of 250 positions): branchless register buckets.
// No atomics, no LDS RMW, statically-indexed regs only (no scratch).
__global__ __launch_bounds__(256) void k_abuild(const int* __restrict__ target, const float* __restrict__ wt,
                                                float* __restrict__ Ag){
    __shared__ int tss[256];
    int b = blockIdx.x >> 2, seg = blockIdx.x & 3;
    int t = threadIdx.x;
    if (t < 250) tss[t] = target[b*PL + seg*250 + t];
    __syncthreads();
    float buck[VOC];
#pragma unroll
    for (int v = 0; v < VOC; ++v) buck[v] = 0.f;
    const float* wtb = wt + (size_t)(seg*250)*256 + t;
    for (int i = 0; i < 250; ++i){
        float w = wtb[(size_t)i*256];   // coalesced 1KB row, independent addresses
        int tok = tss[i];               // wave-uniform LDS broadcast
#pragma unroll
        for (int v = 0; v < VOC; ++v)
            buck[v] += (tok == v) ? w : 0.f;
    }
    float* Ao = Ag + (size_t)blockIdx.x*VOC*256 + t;
#pragma unroll
    for (int v = 0; v < VOC; ++v) Ao[(size_t)v*256] = buck[v];
}

// c[b][o][p] = relu( sum_v sum_k (Σ_seg A)[v][o*8+k]*emb[v][p+k] + cb[o] ), block=(b,half)
__global__ __launch_bounds__(256) void k_conv(const float* __restrict__ Ag, const float* __restrict__ emb,
                                              const float* __restrict__ convb, float* __restrict__ cbuf){
    __shared__ float As[VOC][128];
    __shared__ float embs[VOC*128 + 16];
    int b = blockIdx.x >> 1, half = blockIdx.x & 1;
    int t = threadIdx.x;
    for (int i = t; i < VOC*128; i += 256){
        int v = i >> 7, c = i & 127;
        float s = 0.f;
#pragma unroll
        for (int seg = 0; seg < 4; ++seg)
            s += Ag[((size_t)(b*4 + seg)*VOC + v)*256 + half*128 + c];
        As[v][c] = s;
        embs[i] = emb[i];
    }
    if (t < 16) embs[VOC*128 + t] = 0.f;
    __syncthreads();
    int o_l = t >> 4, pg = t & 15, p0 = pg * 8;
    float accp[8];
#pragma unroll
    for (int i = 0; i < 8; ++i) accp[i] = 0.f;
    for (int v = 0; v < VOC; ++v){
        float w[15];
        const float* er = embs + v*128 + p0;
#pragma unroll
        for (int i = 0; i < 15; ++i) w[i] = er[i];
#pragma unroll
        for (int k2 = 0; k2 < 8; ++k2){
            float a = As[v][o_l*8 + k2];
#pragma unroll
            for (int j = 0; j < 8; ++j) accp[j] += a * w[j + k2];
        }
    }
    float cbv = convb[half*16 + o_l];
#pragma unroll
    for (int j = 0; j < 8; ++j){
        int p = p0 + j;
        if (p < 121){
            float v2 = accp[j] + cbv;
            cbuf[(size_t)b*3872 + (half*16 + o_l)*121 + p] = v2 > 0.f ? v2 : 0.f;
        }
    }
}

__global__ __launch_bounds__(256) void k_xt(const float* __restrict__ cbuf, const float* __restrict__ fxw,
                                            float* __restrict__ xtp){
    __shared__ float csh[16][242];
    int kt = blockIdx.x >> 3, bt = blockIdx.x & 7;
    int t = threadIdx.x;
    for (int i = t; i < 16*242; i += 256){
        int bb = i / 242, kk = i % 242;
        csh[bb][kk] = cbuf[(size_t)(bt*16 + bb)*3872 + kt*242 + kk];
    }
    __syncthreads();
    int j = t & 127, bh = t >> 7;
    float acc[8];
#pragma unroll
    for (int i = 0; i < 8; ++i) acc[i] = 0.f;
    for (int kk = 0; kk < 242; ++kk){
        float w = fxw[(size_t)(kt*242 + kk)*128 + j];
#pragma unroll
        for (int bb = 0; bb < 8; ++bb) acc[bb] += csh[bh*8 + bb][kk] * w;
    }
#pragma unroll
    for (int bb = 0; bb < 8; ++bb)
        xtp[(size_t)kt*NB*128 + (size_t)(bt*16 + bh*8 + bb)*128 + j] = acc[bb];
}

// ---------------- fused head ----------------
__global__ __launch_bounds__(256) void k_fc1(const float* __restrict__ gfc, const float* __restrict__ xtp,
                                             const float* __restrict__ fxb,
                                             const float* __restrict__ w, const float* __restrict__ bias,
                                             float* __restrict__ out){
    __shared__ float xc[256];
    int b = blockIdx.x, t = threadIdx.x;
    if (t < 128) xc[t] = gfc[b*OD + t];
    else {
        int j = t - 128;
        float s = fxb[j];
#pragma unroll
        for (int kt = 0; kt < 16; ++kt) s += xtp[(size_t)kt*NB*128 + (size_t)b*128 + j];
        xc[t] = s;
    }
    __syncthreads();
#pragma unroll
    for (int rep = 0; rep < 4; ++rep){
        int j = t + rep*256;
        float acc = 0.f;
        for (int k = 0; k < 256; ++k) acc += xc[k] * w[(size_t)k*1024 + j];
        acc += bias[j];
        out[b*1024 + j] = acc > 0.f ? acc : 0.f;
    }
}

__global__ __launch_bounds__(256) void k_fc2o(const float* __restrict__ in, const float* __restrict__ w,
                                              const float* __restrict__ bias, const float* __restrict__ ow,
                                              const float* __restrict__ ob, float* __restrict__ out){
    __shared__ float row[1024];
    __shared__ float s2[256];
    int b = blockIdx.x, t = threadIdx.x;
    for (int i = t; i < 1024; i += 256) row[i] = in[b*1024 + i];
    __syncthreads();
    float acc = 0.f;
    for (int k = 0; k < 1024; ++k) acc += row[k] * w[(size_t)k*256 + t];
    acc += bias[t];
    acc = acc > 0.f ? acc : 0.f;
    s2[t] = acc * ow[t];
    __syncthreads();
    if (t < 64){
        float a = s2[t] + s2[t + 64] + s2[t + 128] + s2[t + 192];
#pragma unroll
        for (int o = 32; o; o >>= 1) a += __shfl_xor(a, o);
        if (t == 0) out[b] = a + ob[0];
    }
}

extern "C" void kernel_launch(void* const* d_in, const int* in_sizes, int n_in,
                              void* d_out, int out_size, void* d_ws, size_t ws_size,
                              hipStream_t stream){
    const float* x    = (const float*)d_in[0];
    const int*  ei    = (const int*)d_in[1];
    const int*  batch = (const int*)d_in[2];
    const int*  target= (const int*)d_in[3];
    const float* W1   = (const float*)d_in[4];
    const float* as1w = (const float*)d_in[5];
    const float* ad1w = (const float*)d_in[6];
    const float* b1   = (const float*)d_in[7];
    const float* W2   = (const float*)d_in[8];
    const float* as2w = (const float*)d_in[9];
    const float* ad2w = (const float*)d_in[10];
    const float* b2   = (const float*)d_in[11];
    const float* fgw  = (const float*)d_in[12];
    const float* fgb  = (const float*)d_in[13];
    const float* emb  = (const float*)d_in[14];
    const float* cw   = (const float*)d_in[15];
    const float* cb   = (const float*)d_in[16];
    const float* fxw  = (const float*)d_in[17];
    const float* fxb  = (const float*)d_in[18];
    const float* f1w  = (const float*)d_in[19];
    const float* f1b  = (const float*)d_in[20];
    const float* f2w  = (const float*)d_in[21];
    const float* f2b  = (const float*)d_in[22];
    const float* ow   = (const float*)d_in[23];
    const float* ob   = (const float*)d_in[24];

    float* f = (float*)d_ws;
    size_t o = 0;
    float* agg = f + o; o += (size_t)NN*D1;     // reused as xlp (4*NN*OD <= NN*D1)
    float* h1  = f + o; o += (size_t)NN*D1;     // reused as Ag after k_gemm2 (3.4M <= 12.8M)
    float* as1 = f + o; o += (size_t)NN*HEADS;
    float* ad1 = f + o; o += (size_t)NN*HEADS;
    float* xl2 = f + o; o += (size_t)NN*OD;
    float* h2  = f + o; o += (size_t)NN*OD;
    float* as2 = f + o; o += NN;
    float* ad2 = f + o; o += NN;
    float* gfc = f + o; o += NB*OD;
    float* hf1 = f + o; o += NB*1024;
    float* vas = f + o; o += D1;
    float* vad = f + o; o += D1;
    float* wt  = f + o; o += (size_t)PL*256;
    float* cbuf= f + o; o += (size_t)NB*3872;
    float* xtp = f + o; o += (size_t)16*NB*128;
    int* cnt   = (int*)(f + o); o += NN;
    int* off   = (int*)(f + o); o += NN + 1;
    int* csrc  = (int*)(f + o); o += ET;
    float* xlp = agg;   // agg dead after k_post1
    float* Ag  = h1;    // h1 dead after k_gemm2; abuild launches after k_poolfc
    (void)ws_size; (void)in_sizes; (void)n_in; (void)out_size;

    // CSR by destination
    hipMemsetAsync(cnt, 0, NN*sizeof(int), stream);
    k_hist<<<(ET + 255)/256, 256, 0, stream>>>(ei, cnt);
    k_scan<<<1, 1024, 0, stream>>>(cnt, off);
    hipMemsetAsync(cnt, 0, NN*sizeof(int), stream);
    k_fill<<<(ET + 255)/256, 256, 0, stream>>>(ei, off, cnt, csrc);

    // GAT layer 1 in x-space
    k_va<<<1, 256, 0, stream>>>(W1, as1w, ad1w, vas, vad);
    k_alpha1x<<<NN/64, 256, 0, stream>>>(x, vas, vad, as1, ad1);
    k_gat1x<<<NN, 64, 0, stream>>>(x, as1, ad1, off, csrc, agg);
    k_post1<<<NN/8, 320, 0, stream>>>(agg, W1, b1, h1);

    // GAT layer 2 (K-split GEMM + fused reduce/alpha2)
    k_gemm2<<<(NN/64)*KS, 256, 0, stream>>>(h1, W2, xlp);
    k_red<<<NN/4, 128, 0, stream>>>(xlp, as2w, ad2w, xl2, as2, ad2);
    k_gat2<<<NN, 64, 0, stream>>>(xl2, as2, ad2, off, csrc, b2, h2);

    // pooling + graph fc (fused)
    k_poolfc<<<NB, 128, 0, stream>>>(h2, batch, fgw, fgb, gfc);

    // protein branch
    k_wt<<<1000, 256, 0, stream>>>(cw, wt);
    k_abuild<<<NB*4, 256, 0, stream>>>(target, wt, Ag);
    k_conv<<<NB*2, 256, 0, stream>>>(Ag, emb, cb, cbuf);
    k_xt<<<128, 256, 0, stream>>>(cbuf, fxw, xtp);

    // head
    k_fc1<<<NB, 256, 0, stream>>>(gfc, xtp, fxb, f1w, f1b, hf1);
    k_fc2o<<<NB, 256, 0, stream>>>(hf1, f2w, f2b, ow, ob, (float*)d_out);
}

// Round 10
// 478.373 us; speedup vs baseline: 1.2220x; 1.0281x over previous
//
#include <hip/hip_runtime.h>
#include <hip/hip_bf16.h>

using bf16 = __hip_bfloat16;

#define NN 16384
#define NE 262144
#define ET (NE + NN)
#define NB 128
#define FEAT 78
#define HEADS 10
#define D1 780
#define OD 128
#define PL 1000
#define VOC 26
#define SLOPE 0.2f

// ---------------- CSR build ----------------
__global__ void k_hist(const int* __restrict__ ei, int* __restrict__ cnt){
    int e = blockIdx.x*256 + threadIdx.x;
    if (e >= ET) return;
    int dst = (e < NE) ? ei[NE + e] : (e - NE);
    atomicAdd(&cnt[dst], 1);
}

__global__ __launch_bounds__(1024) void k_scan(const int* __restrict__ cnt, int* __restrict__ off){
    __shared__ int ps[1024];
    int t = threadIdx.x;
    int loc[16]; int s = 0;
#pragma unroll
    for (int j = 0; j < 16; ++j){ loc[j] = cnt[t*16 + j]; s += loc[j]; }
    ps[t] = s; __syncthreads();
    for (int d = 1; d < 1024; d <<= 1){
        int v = (t >= d) ? ps[t - d] : 0;
        __syncthreads();
        ps[t] += v;
        __syncthreads();
    }
    int run = (t == 0) ? 0 : ps[t - 1];
#pragma unroll
    for (int j = 0; j < 16; ++j){ off[t*16 + j] = run; run += loc[j]; }
    if (t == 1023) off[NN] = run;
}

__global__ void k_fill(const int* __restrict__ ei, const int* __restrict__ off,
                       int* __restrict__ cur, int* __restrict__ csrc){
    int e = blockIdx.x*256 + threadIdx.x;
    if (e >= ET) return;
    int src, dst;
    if (e < NE){ src = ei[e]; dst = ei[NE + e]; } else { src = e - NE; dst = src; }
    int p = off[dst] + atomicAdd(&cur[dst], 1);
    csrc[p] = src;
}

// ---------------- GAT layer 1 (x-space) ----------------
__global__ __launch_bounds__(256) void k_va(const float* __restrict__ W1, const float* __restrict__ asw,
                                            const float* __restrict__ adw,
                                            float* __restrict__ vas, float* __restrict__ vad){
    __shared__ float sa[D1], sd[D1];
    int t = threadIdx.x;
    for (int i = t; i < D1; i += 256){ sa[i] = asw[i]; sd[i] = adw[i]; }
    __syncthreads();
    for (int idx = t; idx < D1; idx += 256){
        int h = idx / FEAT, k = idx % FEAT;
        const float* wr = W1 + (size_t)k*D1 + h*FEAT;
        float a = 0.f, d = 0.f;
        for (int j = 0; j < FEAT; ++j){ float w = wr[j]; a += w*sa[h*FEAT + j]; d += w*sd[h*FEAT + j]; }
        vas[idx] = a; vad[idx] = d;
    }
}

__global__ __launch_bounds__(256) void k_alpha1x(const float* __restrict__ x, const float* __restrict__ vas,
                                                 const float* __restrict__ vad,
                                                 float* __restrict__ as1, float* __restrict__ ad1){
    __shared__ float xs[64*79];
    __shared__ float va[D1], vd[D1];
    int n0 = blockIdx.x * 64, t = threadIdx.x;
    for (int i = t; i < D1; i += 256){ va[i] = vas[i]; vd[i] = vad[i]; }
    for (int i = t; i < 64*FEAT; i += 256){
        int n = i / FEAT, k = i % FEAT;
        xs[n*79 + k] = x[(size_t)n0*FEAT + i];
    }
    __syncthreads();
    for (int p = t; p < 64*HEADS; p += 256){
        int h = p >> 6, nl = p & 63;
        const float* xr = xs + nl*79;
        const float* pa = va + h*FEAT; const float* pd = vd + h*FEAT;
        float a = 0.f, d = 0.f;
        for (int k = 0; k < FEAT; ++k){ float xv = xr[k]; a += xv*pa[k]; d += xv*pd[k]; }
        as1[(size_t)(n0 + nl)*HEADS + h] = a;
        ad1[(size_t)(n0 + nl)*HEADS + h] = d;
    }
}

// per dst: lane j owns edge beg+j; wave reductions for softmax; shfl-broadcast agg
__global__ __launch_bounds__(64) void k_gat1x(const float* __restrict__ x, const float* __restrict__ as1,
                                              const float* __restrict__ ad1, const int* __restrict__ off,
                                              const int* __restrict__ csrc,
                                              float* __restrict__ agg){
    int dst = blockIdx.x, lane = threadIdx.x;
    int beg = off[dst], end = off[dst + 1];
    int deg = end - beg;
    float adh[HEADS];
#pragma unroll
    for (int h = 0; h < HEADS; ++h) adh[h] = ad1[(size_t)dst*HEADS + h];
    int s0 = 0;
    float p[HEADS], mx[HEADS];
#pragma unroll
    for (int h = 0; h < HEADS; ++h){ mx[h] = -1e30f; p[h] = 0.f; }
    if (lane < deg){
        s0 = csrc[beg + lane];
#pragma unroll
        for (int h = 0; h < HEADS; ++h){
            float v = as1[(size_t)s0*HEADS + h] + adh[h];
            v = v > 0.f ? v : SLOPE*v;
            p[h] = v; mx[h] = v;
        }
    }
    if (deg > 64){
        for (int e = beg + 64 + lane; e < end; e += 64){
            int s = csrc[e];
#pragma unroll
            for (int h = 0; h < HEADS; ++h){
                float v = as1[(size_t)s*HEADS + h] + adh[h];
                v = v > 0.f ? v : SLOPE*v;
                mx[h] = fmaxf(mx[h], v);
            }
        }
    }
#pragma unroll
    for (int h = 0; h < HEADS; ++h)
        for (int o = 32; o; o >>= 1) mx[h] = fmaxf(mx[h], __shfl_xor(mx[h], o));
    float sm[HEADS];
#pragma unroll
    for (int h = 0; h < HEADS; ++h) sm[h] = 0.f;
    if (lane < deg){
#pragma unroll
        for (int h = 0; h < HEADS; ++h){ p[h] = __expf(p[h] - mx[h]); sm[h] = p[h]; }
    }
    if (deg > 64){
        for (int e = beg + 64 + lane; e < end; e += 64){
            int s = csrc[e];
#pragma unroll
            for (int h = 0; h < HEADS; ++h){
                float v = as1[(size_t)s*HEADS + h] + adh[h];
                v = v > 0.f ? v : SLOPE*v;
                sm[h] += __expf(v - mx[h]);
            }
        }
    }
    float inv[HEADS];
#pragma unroll
    for (int h = 0; h < HEADS; ++h){
        for (int o = 32; o; o >>= 1) sm[h] += __shfl_xor(sm[h], o);
        inv[h] = 1.f/(sm[h] + 1e-16f);
        p[h] = (lane < deg) ? p[h]*inv[h] : 0.f;
    }
    float acc1[HEADS], acc2[HEADS];
#pragma unroll
    for (int h = 0; h < HEADS; ++h){ acc1[h] = 0.f; acc2[h] = 0.f; }
    int cnt0 = deg < 64 ? deg : 64;
    for (int q = 0; q < cnt0; ++q){
        int s = __shfl(s0, q);
        const float* xr = x + (size_t)s*FEAT;
        float xv1 = xr[lane];
        float xv2 = (lane < FEAT - 64) ? xr[64 + lane] : 0.f;
#pragma unroll
        for (int h = 0; h < HEADS; ++h){
            float al = __shfl(p[h], q);
            acc1[h] += al*xv1;
            acc2[h] += al*xv2;
        }
    }
    if (deg > 64){
        for (int base = beg + 64; base < end; base += 64){
            int cnt = min(64, end - base);
            int s1 = 0;
            float pp[HEADS];
#pragma unroll
            for (int h = 0; h < HEADS; ++h) pp[h] = 0.f;
            if (lane < cnt){
                s1 = csrc[base + lane];
#pragma unroll
                for (int h = 0; h < HEADS; ++h){
                    float v = as1[(size_t)s1*HEADS + h] + adh[h];
                    v = v > 0.f ? v : SLOPE*v;
                    pp[h] = __expf(v - mx[h])*inv[h];
                }
            }
            for (int q = 0; q < cnt; ++q){
                int s = __shfl(s1, q);
                const float* xr = x + (size_t)s*FEAT;
                float xv1 = xr[lane];
                float xv2 = (lane < FEAT - 64) ? xr[64 + lane] : 0.f;
#pragma unroll
                for (int h = 0; h < HEADS; ++h){
                    float al = __shfl(pp[h], q);
                    acc1[h] += al*xv1;
                    acc2[h] += al*xv2;
                }
            }
        }
    }
#pragma unroll
    for (int h = 0; h < HEADS; ++h)
        agg[(size_t)dst*D1 + h*FEAT + lane] = acc1[h];
    if (lane < FEAT - 64){
#pragma unroll
        for (int h = 0; h < HEADS; ++h)
            agg[(size_t)dst*D1 + h*FEAT + 64 + lane] = acc2[h];
    }
}

__global__ __launch_bounds__(320) void k_post1(const float* __restrict__ agg, const float* __restrict__ W1,
                                               const float* __restrict__ b1, float* __restrict__ h1){
    __shared__ __align__(16) float ags[8][800];
    int r0 = blockIdx.x * 8, t = threadIdx.x;
    for (int i = t; i < 8*D1; i += 320){
        int r = i / D1, c = i % D1, h = c / FEAT, j = c % FEAT;
        ags[r][h*80 + j] = agg[(size_t)(r0 + r)*D1 + c];
    }
    __syncthreads();
    if (t < 260){
        int h = t / 26, jj = (t % 26)*3;
        int cb = h*FEAT + jj;
        const float* wcol = W1 + cb;
        float acc[8][3];
#pragma unroll
        for (int r = 0; r < 8; ++r){ acc[r][0] = 0.f; acc[r][1] = 0.f; acc[r][2] = 0.f; }
        int k = 0;
        for (; k + 4 <= FEAT; k += 4){
            float4 a[8];
#pragma unroll
            for (int r = 0; r < 8; ++r) a[r] = *(const float4*)&ags[r][h*80 + k];
#pragma unroll
            for (int kk = 0; kk < 4; ++kk){
                const float* wr = wcol + (size_t)(k + kk)*D1;
                float w0 = wr[0], w1 = wr[1], w2 = wr[2];
#pragma unroll
                for (int r = 0; r < 8; ++r){
                    float av = ((const float*)&a[r])[kk];
                    acc[r][0] += av*w0; acc[r][1] += av*w1; acc[r][2] += av*w2;
                }
            }
        }
        for (; k < FEAT; ++k){
            const float* wr = wcol + (size_t)k*D1;
            float w0 = wr[0], w1 = wr[1], w2 = wr[2];
#pragma unroll
            for (int r = 0; r < 8; ++r){
                float av = ags[r][h*80 + k];
                acc[r][0] += av*w0; acc[r][1] += av*w1; acc[r][2] += av*w2;
            }
        }
        float bv0 = b1[cb], bv1 = b1[cb+1], bv2 = b1[cb+2];
#pragma unroll
        for (int r = 0; r < 8; ++r){
            float v0 = acc[r][0] + bv0, v1 = acc[r][1] + bv1, v2 = acc[r][2] + bv2;
            v0 = v0 > 0.f ? v0 : __expf(v0) - 1.f;
            v1 = v1 > 0.f ? v1 : __expf(v1) - 1.f;
            v2 = v2 > 0.f ? v2 : __expf(v2) - 1.f;
            size_t base = (size_t)(r0 + r)*D1 + cb;
            h1[base] = v0; h1[base+1] = v1; h1[base+2] = v2;
        }
    }
}

// ---------------- GAT layer 2 GEMM: 64x128 tile, K-split x4 ----------------
#define KC 39
#define KS 4
#define KSEG 195
__global__ __launch_bounds__(256) void k_gemm2(const float* __restrict__ h1, const float* __restrict__ W2,
                                               float* __restrict__ xlp){
    __shared__ __align__(16) float as[KC][68];
    __shared__ __align__(16) float ws[KC][128];
    int bid = blockIdx.x;
    int ks = bid & (KS - 1);
    int r0 = (bid >> 2) * 64;
    int t = threadIdx.x;
    int rg = t >> 5, jq = t & 31;
    float acc[8][4];
#pragma unroll
    for (int i = 0; i < 8; ++i)
#pragma unroll
        for (int j = 0; j < 4; ++j) acc[i][j] = 0.f;
    for (int kc = ks*KSEG; kc < ks*KSEG + KSEG; kc += KC){
        for (int i = t; i < 64*KC; i += 256){
            int r = i / KC, k = i % KC;
            as[k][r] = h1[(size_t)(r0 + r)*D1 + kc + k];
        }
        for (int i = t; i < KC*128; i += 256){
            int k = i >> 7, j = i & 127;
            ws[k][j] = W2[(size_t)(kc + k)*OD + j];
        }
        __syncthreads();
        for (int k = 0; k < KC; ++k){
            float4 a0 = *(const float4*)&as[k][rg*8];
            float4 a1 = *(const float4*)&as[k][rg*8 + 4];
            float4 w4 = *(const float4*)&ws[k][jq*4];
            float av[8] = {a0.x, a0.y, a0.z, a0.w, a1.x, a1.y, a1.z, a1.w};
            float wv[4] = {w4.x, w4.y, w4.z, w4.w};
#pragma unroll
            for (int i = 0; i < 8; ++i)
#pragma unroll
                for (int j = 0; j < 4; ++j) acc[i][j] += av[i]*wv[j];
        }
        __syncthreads();
    }
    float* dst = xlp + (size_t)ks*NN*OD;
#pragma unroll
    for (int i = 0; i < 8; ++i){
        float4 o4 = make_float4(acc[i][0], acc[i][1], acc[i][2], acc[i][3]);
        *(float4*)&dst[(size_t)(r0 + rg*8 + i)*OD + jq*4] = o4;
    }
}

// reduce 4 partials -> xl2, fused alpha2
__global__ __launch_bounds__(128) void k_red(const float* __restrict__ xlp,
                                             const float* __restrict__ s2w, const float* __restrict__ d2w,
                                             float* __restrict__ xl2,
                                             float* __restrict__ as2, float* __restrict__ ad2){
    const size_t Q = (size_t)NN*OD/4;
    int t = threadIdx.x;
    size_t fi = (size_t)blockIdx.x*128 + t;
    const float4* P = (const float4*)xlp;
    float4 a = P[fi], b = P[fi + Q], c = P[fi + 2*Q], d = P[fi + 3*Q];
    float4 v = make_float4(a.x+b.x+c.x+d.x, a.y+b.y+c.y+d.y,
                           a.z+b.z+c.z+d.z, a.w+b.w+c.w+d.w);
    ((float4*)xl2)[fi] = v;
    int cc = (t & 31)*4;
    float sa = v.x*s2w[cc] + v.y*s2w[cc+1] + v.z*s2w[cc+2] + v.w*s2w[cc+3];
    float sd = v.x*d2w[cc] + v.y*d2w[cc+1] + v.z*d2w[cc+2] + v.w*d2w[cc+3];
#pragma unroll
    for (int o = 16; o; o >>= 1){ sa += __shfl_xor(sa, o); sd += __shfl_xor(sd, o); }
    if ((t & 31) == 0){
        int n = blockIdx.x*4 + (t >> 5);
        as2[n] = sa; ad2[n] = sd;
    }
}

// per dst: lane-owned alpha + shfl broadcast
__global__ __launch_bounds__(64) void k_gat2(const float* __restrict__ xl2, const float* __restrict__ as2,
                                             const float* __restrict__ ad2, const int* __restrict__ off,
                                             const int* __restrict__ csrc, const float* __restrict__ b2,
                                             float* __restrict__ h2){
    int dst = blockIdx.x, lane = threadIdx.x;
    int beg = off[dst], end = off[dst + 1];
    int deg = end - beg;
    float ad = ad2[dst];
    int s0 = 0; float v0 = -1e30f;
    if (lane < deg){
        s0 = csrc[beg + lane];
        float v = as2[s0] + ad;
        v0 = v > 0.f ? v : SLOPE*v;
    }
    float m = v0;
    if (deg > 64){
        for (int e = beg + 64 + lane; e < end; e += 64){
            float v = as2[csrc[e]] + ad; v = v > 0.f ? v : SLOPE*v;
            m = fmaxf(m, v);
        }
    }
    for (int o = 32; o; o >>= 1) m = fmaxf(m, __shfl_xor(m, o));
    float pe = (lane < deg) ? __expf(v0 - m) : 0.f;
    float sm = pe;
    if (deg > 64){
        for (int e = beg + 64 + lane; e < end; e += 64){
            float v = as2[csrc[e]] + ad; v = v > 0.f ? v : SLOPE*v;
            sm += __expf(v - m);
        }
    }
    for (int o = 32; o; o >>= 1) sm += __shfl_xor(sm, o);
    float inv = 1.f / (sm + 1e-16f);
    float p = pe * inv;
    float a0 = 0.f, a1 = 0.f;
    int cnt0 = deg < 64 ? deg : 64;
    for (int q = 0; q < cnt0; ++q){
        int s = __shfl(s0, q);
        float al = __shfl(p, q);
        a0 += al * xl2[(size_t)s*OD + lane];
        a1 += al * xl2[(size_t)s*OD + 64 + lane];
    }
    if (deg > 64){
        for (int base = beg + 64; base < end; base += 64){
            int cnt = min(64, end - base);
            int s1 = 0; float pp = 0.f;
            if (lane < cnt){
                s1 = csrc[base + lane];
                float v = as2[s1] + ad; v = v > 0.f ? v : SLOPE*v;
                pp = __expf(v - m) * inv;
            }
            for (int q = 0; q < cnt; ++q){
                int s = __shfl(s1, q);
                float al = __shfl(pp, q);
                a0 += al * xl2[(size_t)s*OD + lane];
                a1 += al * xl2[(size_t)s*OD + 64 + lane];
            }
        }
    }
    float o0 = a0 + b2[lane];      o0 = o0 > 0.f ? o0 : 0.f;
    float o1 = a1 + b2[64 + lane]; o1 = o1 > 0.f ? o1 : 0.f;
    h2[(size_t)dst*OD + lane] = o0;
    h2[(size_t)dst*OD + 64 + lane] = o1;
}

// ---------------- pooling + graph FC (fused) ----------------
__global__ __launch_bounds__(128) void k_poolfc(const float* __restrict__ h2, const int* __restrict__ batch,
                                                const float* __restrict__ w, const float* __restrict__ bias,
                                                float* __restrict__ gfc){
    __shared__ float row[OD];
    int b = blockIdx.x, t = threadIdx.x;
    int lo = 0, hi = NN;
    while (lo < hi){ int mid = (lo + hi) >> 1; if (batch[mid] < b) lo = mid + 1; else hi = mid; }
    int s0 = lo;
    lo = s0; hi = NN;
    while (lo < hi){ int mid = (lo + hi) >> 1; if (batch[mid] < b + 1) lo = mid + 1; else hi = mid; }
    int s1 = lo;
    float mx = 0.f;
    for (int n = s0; n < s1; ++n) mx = fmaxf(mx, h2[(size_t)n*OD + t]);
    row[t] = mx;
    __syncthreads();
    float acc = 0.f;
    for (int k = 0; k < OD; ++k) acc += row[k] * w[k*OD + t];
    acc += bias[t];
    gfc[b*OD + t] = acc > 0.f ? acc : 0.f;
}

// ---------------- protein branch ----------------
// one-time transpose: wt[i][o*8+k] = convw[o][i][k]  (coalesced A-build loads)
__global__ __launch_bounds__(256) void k_wt(const float* __restrict__ convw, float* __restrict__ wt){
    int idx = blockIdx.x*256 + threadIdx.x;
    int i = idx >> 8, ok = idx & 255;
    wt[idx] = convw[(size_t)(ok >> 3)*PL*8 + (size_t)i*8 + (ok & 7)];
}

// A-partials per (b, seg of 250 positions): fixed-point + native integer LDS
// atomics (ds_add_u32, fire-and-forget; exact integer commutativity = deterministic).
__global__ __launch_bounds__(256) void k_abuild(const int* __restrict__ target, const float* __restrict__ wt,
                                                float* __restrict__ Ag){
    __shared__ int Ai[VOC][256];
    __shared__ int tss[256];
    int b = blockIdx.x >> 2, seg = blockIdx.x & 3;
    int t = threadIdx.x;
#pragma unroll
    for (int v = 0; v < VOC; ++v) Ai[v][t] = 0;
    if (t < 250) tss[t] = target[b*PL + seg*250 + t];
    __syncthreads();
    const float* wtb = wt + (size_t)(seg*250)*256 + t;
    const float SC = 16777216.0f;               // 2^24
    for (int i = 0; i < 250; ++i){
        float w = wtb[(size_t)i*256];           // coalesced, independent addresses
        int q = __float2int_rn(w * SC);
        atomicAdd(&Ai[tss[i]][t], q);           // native ds_add_u32, no return
    }
    __syncthreads();
    const float INV = 5.9604644775390625e-08f;  // 2^-24
    float* Ao = Ag + (size_t)blockIdx.x*VOC*256 + t;
#pragma unroll
    for (int v = 0; v < VOC; ++v) Ao[(size_t)v*256] = (float)Ai[v][t] * INV;
}

// c[b][o][p] = relu( sum_v sum_k (Σ_seg A)[v][o*8+k]*emb[v][p+k] + cb[o] ), block=(b,half)
__global__ __launch_bounds__(256) void k_conv(const float* __restrict__ Ag, const float* __restrict__ emb,
                                              const float* __restrict__ convb, float* __restrict__ cbuf){
    __shared__ float As[VOC][128];
    __shared__ float embs[VOC*128 + 16];
    int b = blockIdx.x >> 1, half = blockIdx.x & 1;
    int t = threadIdx.x;
    for (int i = t; i < VOC*128; i += 256){
        int v = i >> 7, c = i & 127;
        float s = 0.f;
#pragma unroll
        for (int seg = 0; seg < 4; ++seg)
            s += Ag[((size_t)(b*4 + seg)*VOC + v)*256 + half*128 + c];
        As[v][c] = s;
        embs[i] = emb[i];
    }
    if (t < 16) embs[VOC*128 + t] = 0.f;
    __syncthreads();
    int o_l = t >> 4, pg = t & 15, p0 = pg * 8;
    float accp[8];
#pragma unroll
    for (int i = 0; i < 8; ++i) accp[i] = 0.f;
    for (int v = 0; v < VOC; ++v){
        float w[15];
        const float* er = embs + v*128 + p0;
#pragma unroll
        for (int i = 0; i < 15; ++i) w[i] = er[i];
#pragma unroll
        for (int k2 = 0; k2 < 8; ++k2){
            float a = As[v][o_l*8 + k2];
#pragma unroll
            for (int j = 0; j < 8; ++j) accp[j] += a * w[j + k2];
        }
    }
    float cbv = convb[half*16 + o_l];
#pragma unroll
    for (int j = 0; j < 8; ++j){
        int p = p0 + j;
        if (p < 121){
            float v2 = accp[j] + cbv;
            cbuf[(size_t)b*3872 + (half*16 + o_l)*121 + p] = v2 > 0.f ? v2 : 0.f;
        }
    }
}

__global__ __launch_bounds__(256) void k_xt(const float* __restrict__ cbuf, const float* __restrict__ fxw,
                                            float* __restrict__ xtp){
    __shared__ float csh[16][242];
    int kt = blockIdx.x >> 3, bt = blockIdx.x & 7;
    int t = threadIdx.x;
    for (int i = t; i < 16*242; i += 256){
        int bb = i / 242, kk = i % 242;
        csh[bb][kk] = cbuf[(size_t)(bt*16 + bb)*3872 + kt*242 + kk];
    }
    __syncthreads();
    int j = t & 127, bh = t >> 7;
    float acc[8];
#pragma unroll
    for (int i = 0; i < 8; ++i) acc[i] = 0.f;
    for (int kk = 0; kk < 242; ++kk){
        float w = fxw[(size_t)(kt*242 + kk)*128 + j];
#pragma unroll
        for (int bb = 0; bb < 8; ++bb) acc[bb] += csh[bh*8 + bb][kk] * w;
    }
#pragma unroll
    for (int bb = 0; bb < 8; ++bb)
        xtp[(size_t)kt*NB*128 + (size_t)(bt*16 + bh*8 + bb)*128 + j] = acc[bb];
}

// ---------------- fused head ----------------
__global__ __launch_bounds__(256) void k_fc1(const float* __restrict__ gfc, const float* __restrict__ xtp,
                                             const float* __restrict__ fxb,
                                             const float* __restrict__ w, const float* __restrict__ bias,
                                             float* __restrict__ out){
    __shared__ float xc[256];
    int b = blockIdx.x, t = threadIdx.x;
    if (t < 128) xc[t] = gfc[b*OD + t];
    else {
        int j = t - 128;
        float s = fxb[j];
#pragma unroll
        for (int kt = 0; kt < 16; ++kt) s += xtp[(size_t)kt*NB*128 + (size_t)b*128 + j];
        xc[t] = s;
    }
    __syncthreads();
#pragma unroll
    for (int rep = 0; rep < 4; ++rep){
        int j = t + rep*256;
        float acc = 0.f;
        for (int k = 0; k < 256; ++k) acc += xc[k] * w[(size_t)k*1024 + j];
        acc += bias[j];
        out[b*1024 + j] = acc > 0.f ? acc : 0.f;
    }
}

__global__ __launch_bounds__(256) void k_fc2o(const float* __restrict__ in, const float* __restrict__ w,
                                              const float* __restrict__ bias, const float* __restrict__ ow,
                                              const float* __restrict__ ob, float* __restrict__ out){
    __shared__ float row[1024];
    __shared__ float s2[256];
    int b = blockIdx.x, t = threadIdx.x;
    for (int i = t; i < 1024; i += 256) row[i] = in[b*1024 + i];
    __syncthreads();
    float acc = 0.f;
    for (int k = 0; k < 1024; ++k) acc += row[k] * w[(size_t)k*256 + t];
    acc += bias[t];
    acc = acc > 0.f ? acc : 0.f;
    s2[t] = acc * ow[t];
    __syncthreads();
    if (t < 64){
        float a = s2[t] + s2[t + 64] + s2[t + 128] + s2[t + 192];
#pragma unroll
        for (int o = 32; o; o >>= 1) a += __shfl_xor(a, o);
        if (t == 0) out[b] = a + ob[0];
    }
}

extern "C" void kernel_launch(void* const* d_in, const int* in_sizes, int n_in,
                              void* d_out, int out_size, void* d_ws, size_t ws_size,
                              hipStream_t stream){
    const float* x    = (const float*)d_in[0];
    const int*  ei    = (const int*)d_in[1];
    const int*  batch = (const int*)d_in[2];
    const int*  target= (const int*)d_in[3];
    const float* W1   = (const float*)d_in[4];
    const float* as1w = (const float*)d_in[5];
    const float* ad1w = (const float*)d_in[6];
    const float* b1   = (const float*)d_in[7];
    const float* W2   = (const float*)d_in[8];
    const float* as2w = (const float*)d_in[9];
    const float* ad2w = (const float*)d_in[10];
    const float* b2   = (const float*)d_in[11];
    const float* fgw  = (const float*)d_in[12];
    const float* fgb  = (const float*)d_in[13];
    const float* emb  = (const float*)d_in[14];
    const float* cw   = (const float*)d_in[15];
    const float* cb   = (const float*)d_in[16];
    const float* fxw  = (const float*)d_in[17];
    const float* fxb  = (const float*)d_in[18];
    const float* f1w  = (const float*)d_in[19];
    const float* f1b  = (const float*)d_in[20];
    const float* f2w  = (const float*)d_in[21];
    const float* f2b  = (const float*)d_in[22];
    const float* ow   = (const float*)d_in[23];
    const float* ob   = (const float*)d_in[24];

    float* f = (float*)d_ws;
    size_t o = 0;
    float* agg = f + o; o += (size_t)NN*D1;     // reused as xlp (4*NN*OD <= NN*D1)
    float* h1  = f + o; o += (size_t)NN*D1;     // reused as Ag after k_gemm2 (3.4M <= 12.8M)
    float* as1 = f + o; o += (size_t)NN*HEADS;
    float* ad1 = f + o; o += (size_t)NN*HEADS;
    float* xl2 = f + o; o += (size_t)NN*OD;
    float* h2  = f + o; o += (size_t)NN*OD;
    float* as2 = f + o; o += NN;
    float* ad2 = f + o; o += NN;
    float* gfc = f + o; o += NB*OD;
    float* hf1 = f + o; o += NB*1024;
    float* vas = f + o; o += D1;
    float* vad = f + o; o += D1;
    float* wt  = f + o; o += (size_t)PL*256;
    float* cbuf= f + o; o += (size_t)NB*3872;
    float* xtp = f + o; o += (size_t)16*NB*128;
    int* cnt   = (int*)(f + o); o += NN;
    int* off   = (int*)(f + o); o += NN + 1;
    int* csrc  = (int*)(f + o); o += ET;
    float* xlp = agg;   // agg dead after k_post1
    float* Ag  = h1;    // h1 dead after k_gemm2; abuild launches after k_poolfc
    (void)ws_size; (void)in_sizes; (void)n_in; (void)out_size;

    // CSR by destination
    hipMemsetAsync(cnt, 0, NN*sizeof(int), stream);
    k_hist<<<(ET + 255)/256, 256, 0, stream>>>(ei, cnt);
    k_scan<<<1, 1024, 0, stream>>>(cnt, off);
    hipMemsetAsync(cnt, 0, NN*sizeof(int), stream);
    k_fill<<<(ET + 255)/256, 256, 0, stream>>>(ei, off, cnt, csrc);

    // GAT layer 1 in x-space
    k_va<<<1, 256, 0, stream>>>(W1, as1w, ad1w, vas, vad);
    k_alpha1x<<<NN/64, 256, 0, stream>>>(x, vas, vad, as1, ad1);
    k_gat1x<<<NN, 64, 0, stream>>>(x, as1, ad1, off, csrc, agg);
    k_post1<<<NN/8, 320, 0, stream>>>(agg, W1, b1, h1);

    // GAT layer 2 (K-split GEMM + fused reduce/alpha2)
    k_gemm2<<<(NN/64)*KS, 256, 0, stream>>>(h1, W2, xlp);
    k_red<<<NN/4, 128, 0, stream>>>(xlp, as2w, ad2w, xl2, as2, ad2);
    k_gat2<<<NN, 64, 0, stream>>>(xl2, as2, ad2, off, csrc, b2, h2);

    // pooling + graph fc (fused)
    k_poolfc<<<NB, 128, 0, stream>>>(h2, batch, fgw, fgb, gfc);

    // protein branch
    k_wt<<<1000, 256, 0, stream>>>(cw, wt);
    k_abuild<<<NB*4, 256, 0, stream>>>(target, wt, Ag);
    k_conv<<<NB*2, 256, 0, stream>>>(Ag, emb, cb, cbuf);
    k_xt<<<128, 256, 0, stream>>>(cbuf, fxw, xtp);

    // head
    k_fc1<<<NB, 256, 0, stream>>>(gfc, xtp, fxb, f1w, f1b, hf1);
    k_fc2o<<<NB, 256, 0, stream>>>(hf1, f2w, f2b, ow, ob, (float*)d_out);
}

// Round 11
// 464.789 us; speedup vs baseline: 1.2577x; 1.0292x over previous
//
#include <hip/hip_runtime.h>
#include <hip/hip_bf16.h>

using bf16 = __hip_bfloat16;

#define NN 16384
#define NE 262144
#define ET (NE + NN)
#define NB 128
#define FEAT 78
#define HEADS 10
#define D1 780
#define OD 128
#define PL 1000
#define VOC 26
#define SLOPE 0.2f

// ---------------- CSR build ----------------
__global__ void k_hist(const int* __restrict__ ei, int* __restrict__ cnt){
    int e = blockIdx.x*256 + threadIdx.x;
    if (e >= ET) return;
    int dst = (e < NE) ? ei[NE + e] : (e - NE);
    atomicAdd(&cnt[dst], 1);
}

__global__ __launch_bounds__(1024) void k_scan(const int* __restrict__ cnt, int* __restrict__ off){
    __shared__ int ps[1024];
    int t = threadIdx.x;
    int loc[16]; int s = 0;
#pragma unroll
    for (int j = 0; j < 16; ++j){ loc[j] = cnt[t*16 + j]; s += loc[j]; }
    ps[t] = s; __syncthreads();
    for (int d = 1; d < 1024; d <<= 1){
        int v = (t >= d) ? ps[t - d] : 0;
        __syncthreads();
        ps[t] += v;
        __syncthreads();
    }
    int run = (t == 0) ? 0 : ps[t - 1];
#pragma unroll
    for (int j = 0; j < 16; ++j){ off[t*16 + j] = run; run += loc[j]; }
    if (t == 1023) off[NN] = run;
}

__global__ void k_fill(const int* __restrict__ ei, const int* __restrict__ off,
                       int* __restrict__ cur, int* __restrict__ csrc){
    int e = blockIdx.x*256 + threadIdx.x;
    if (e >= ET) return;
    int src, dst;
    if (e < NE){ src = ei[e]; dst = ei[NE + e]; } else { src = e - NE; dst = src; }
    int p = off[dst] + atomicAdd(&cur[dst], 1);
    csrc[p] = src;
}

// ---------------- GAT layer 1 (x-space) ----------------
__global__ __launch_bounds__(256) void k_va(const float* __restrict__ W1, const float* __restrict__ asw,
                                            const float* __restrict__ adw,
                                            float* __restrict__ vas, float* __restrict__ vad){
    __shared__ float sa[D1], sd[D1];
    int t = threadIdx.x;
    for (int i = t; i < D1; i += 256){ sa[i] = asw[i]; sd[i] = adw[i]; }
    __syncthreads();
    for (int idx = t; idx < D1; idx += 256){
        int h = idx / FEAT, k = idx % FEAT;
        const float* wr = W1 + (size_t)k*D1 + h*FEAT;
        float a = 0.f, d = 0.f;
        for (int j = 0; j < FEAT; ++j){ float w = wr[j]; a += w*sa[h*FEAT + j]; d += w*sd[h*FEAT + j]; }
        vas[idx] = a; vad[idx] = d;
    }
}

__global__ __launch_bounds__(256) void k_alpha1x(const float* __restrict__ x, const float* __restrict__ vas,
                                                 const float* __restrict__ vad,
                                                 float* __restrict__ as1, float* __restrict__ ad1){
    __shared__ float xs[64*79];
    __shared__ float va[D1], vd[D1];
    int n0 = blockIdx.x * 64, t = threadIdx.x;
    for (int i = t; i < D1; i += 256){ va[i] = vas[i]; vd[i] = vad[i]; }
    for (int i = t; i < 64*FEAT; i += 256){
        int n = i / FEAT, k = i % FEAT;
        xs[n*79 + k] = x[(size_t)n0*FEAT + i];
    }
    __syncthreads();
    for (int p = t; p < 64*HEADS; p += 256){
        int h = p >> 6, nl = p & 63;
        const float* xr = xs + nl*79;
        const float* pa = va + h*FEAT; const float* pd = vd + h*FEAT;
        float a = 0.f, d = 0.f;
        for (int k = 0; k < FEAT; ++k){ float xv = xr[k]; a += xv*pa[k]; d += xv*pd[k]; }
        as1[(size_t)(n0 + nl)*HEADS + h] = a;
        ad1[(size_t)(n0 + nl)*HEADS + h] = d;
    }
}

// per dst: lane j owns edge beg+j; chunk-register staged gather (16 edges in flight)
__global__ __launch_bounds__(64) void k_gat1x(const float* __restrict__ x, const float* __restrict__ as1,
                                              const float* __restrict__ ad1, const int* __restrict__ off,
                                              const int* __restrict__ csrc,
                                              float* __restrict__ agg){
    int dst = blockIdx.x, lane = threadIdx.x;
    int beg = off[dst], end = off[dst + 1];
    int deg = end - beg;
    float adh[HEADS];
#pragma unroll
    for (int h = 0; h < HEADS; ++h) adh[h] = ad1[(size_t)dst*HEADS + h];
    int s0 = 0;
    float p[HEADS], mx[HEADS];
#pragma unroll
    for (int h = 0; h < HEADS; ++h){ mx[h] = -1e30f; p[h] = 0.f; }
    if (lane < deg){
        s0 = csrc[beg + lane];
#pragma unroll
        for (int h = 0; h < HEADS; ++h){
            float v = as1[(size_t)s0*HEADS + h] + adh[h];
            v = v > 0.f ? v : SLOPE*v;
            p[h] = v; mx[h] = v;
        }
    }
    if (deg > 64){
        for (int e = beg + 64 + lane; e < end; e += 64){
            int s = csrc[e];
#pragma unroll
            for (int h = 0; h < HEADS; ++h){
                float v = as1[(size_t)s*HEADS + h] + adh[h];
                v = v > 0.f ? v : SLOPE*v;
                mx[h] = fmaxf(mx[h], v);
            }
        }
    }
#pragma unroll
    for (int h = 0; h < HEADS; ++h)
        for (int o = 32; o; o >>= 1) mx[h] = fmaxf(mx[h], __shfl_xor(mx[h], o));
    float sm[HEADS];
#pragma unroll
    for (int h = 0; h < HEADS; ++h) sm[h] = 0.f;
    if (lane < deg){
#pragma unroll
        for (int h = 0; h < HEADS; ++h){ p[h] = __expf(p[h] - mx[h]); sm[h] = p[h]; }
    }
    if (deg > 64){
        for (int e = beg + 64 + lane; e < end; e += 64){
            int s = csrc[e];
#pragma unroll
            for (int h = 0; h < HEADS; ++h){
                float v = as1[(size_t)s*HEADS + h] + adh[h];
                v = v > 0.f ? v : SLOPE*v;
                sm[h] += __expf(v - mx[h]);
            }
        }
    }
    float inv[HEADS];
#pragma unroll
    for (int h = 0; h < HEADS; ++h){
        for (int o = 32; o; o >>= 1) sm[h] += __shfl_xor(sm[h], o);
        inv[h] = 1.f/(sm[h] + 1e-16f);
        p[h] = (lane < deg) ? p[h]*inv[h] : 0.f;
    }
    float acc1[HEADS], acc2[HEADS];
#pragma unroll
    for (int h = 0; h < HEADS; ++h){ acc1[h] = 0.f; acc2[h] = 0.f; }
    int cnt0 = deg < 64 ? deg : 64;
    for (int c0 = 0; c0 < cnt0; c0 += 16){
        float r1[16], r2[16];
#pragma unroll
        for (int i = 0; i < 16; ++i){            // 32 independent loads in flight
            int s = __shfl(s0, c0 + i);          // garbage s (=0) for q>=cnt0: harmless
            const float* xr = x + (size_t)s*FEAT;
            r1[i] = xr[lane];
            r2[i] = (lane < FEAT - 64) ? xr[64 + lane] : 0.f;
        }
#pragma unroll
        for (int i = 0; i < 16; ++i){            // static reg indices only (no scratch)
            if (c0 + i < cnt0){
#pragma unroll
                for (int h = 0; h < HEADS; ++h){
                    float al = __shfl(p[h], c0 + i);   // p[h]=0 beyond deg anyway
                    acc1[h] += al*r1[i];
                    acc2[h] += al*r2[i];
                }
            }
        }
    }
    if (deg > 64){
        for (int base = beg + 64; base < end; base += 64){
            int cnt = min(64, end - base);
            int s1 = 0;
            float pp[HEADS];
#pragma unroll
            for (int h = 0; h < HEADS; ++h) pp[h] = 0.f;
            if (lane < cnt){
                s1 = csrc[base + lane];
#pragma unroll
                for (int h = 0; h < HEADS; ++h){
                    float v = as1[(size_t)s1*HEADS + h] + adh[h];
                    v = v > 0.f ? v : SLOPE*v;
                    pp[h] = __expf(v - mx[h])*inv[h];
                }
            }
            for (int c0 = 0; c0 < cnt; c0 += 16){
                float r1[16], r2[16];
#pragma unroll
                for (int i = 0; i < 16; ++i){
                    int s = __shfl(s1, c0 + i);
                    const float* xr = x + (size_t)s*FEAT;
                    r1[i] = xr[lane];
                    r2[i] = (lane < FEAT - 64) ? xr[64 + lane] : 0.f;
                }
#pragma unroll
                for (int i = 0; i < 16; ++i){
                    if (c0 + i < cnt){
#pragma unroll
                        for (int h = 0; h < HEADS; ++h){
                            float al = __shfl(pp[h], c0 + i);
                            acc1[h] += al*r1[i];
                            acc2[h] += al*r2[i];
                        }
                    }
                }
            }
        }
    }
#pragma unroll
    for (int h = 0; h < HEADS; ++h)
        agg[(size_t)dst*D1 + h*FEAT + lane] = acc1[h];
    if (lane < FEAT - 64){
#pragma unroll
        for (int h = 0; h < HEADS; ++h)
            agg[(size_t)dst*D1 + h*FEAT + 64 + lane] = acc2[h];
    }
}

// block = (head, node-tile-64): W1 head-block + agg tile in LDS, 4x6 register tile
__global__ __launch_bounds__(256) void k_post1(const float* __restrict__ agg, const float* __restrict__ W1,
                                               const float* __restrict__ b1, float* __restrict__ h1){
    __shared__ float w1s[FEAT][80];
    __shared__ float ags[64][81];   // pad 81: breaks 16r%32 bank aliasing on a-reads
    __shared__ float bsh[FEAT];
    int ht = blockIdx.x >> 8;       // grid = 10*256
    int nt = blockIdx.x & 255;
    int n0 = nt * 64;
    int t = threadIdx.x;
    for (int i = t; i < FEAT*FEAT; i += 256){
        int k = i / FEAT, j = i % FEAT;
        w1s[k][j] = W1[(size_t)k*D1 + ht*FEAT + j];
    }
    for (int i = t; i < 64*FEAT; i += 256){
        int r = i / FEAT, k = i % FEAT;
        ags[r][k] = agg[(size_t)(n0 + r)*D1 + ht*FEAT + k];
    }
    if (t < FEAT) bsh[t] = b1[ht*FEAT + t];
    __syncthreads();
    if (t < 208){
        int rg = t / 13, cg = t % 13;   // 16 row-groups x4 rows, 13 col-groups x6 cols
        int c0 = cg*6;
        float acc[4][6];
#pragma unroll
        for (int i = 0; i < 4; ++i)
#pragma unroll
            for (int j = 0; j < 6; ++j) acc[i][j] = 0.f;
        for (int k = 0; k < FEAT; ++k){
            float av[4];
#pragma unroll
            for (int i = 0; i < 4; ++i) av[i] = ags[rg*4 + i][k];
            float2 w01 = *(const float2*)&w1s[k][c0];
            float2 w23 = *(const float2*)&w1s[k][c0 + 2];
            float2 w45 = *(const float2*)&w1s[k][c0 + 4];
            float wv[6] = {w01.x, w01.y, w23.x, w23.y, w45.x, w45.y};
#pragma unroll
            for (int i = 0; i < 4; ++i)
#pragma unroll
                for (int j = 0; j < 6; ++j) acc[i][j] += av[i]*wv[j];
        }
#pragma unroll
        for (int i = 0; i < 4; ++i){
#pragma unroll
            for (int j = 0; j < 6; ++j){
                float v = acc[i][j] + bsh[c0 + j];
                v = v > 0.f ? v : __expf(v) - 1.f;   // ELU
                h1[(size_t)(n0 + rg*4 + i)*D1 + ht*FEAT + c0 + j] = v;
            }
        }
    }
}

// ---------------- GAT layer 2 GEMM: 64x128 tile, K-split x4 ----------------
#define KC 39
#define KS 4
#define KSEG 195
__global__ __launch_bounds__(256) void k_gemm2(const float* __restrict__ h1, const float* __restrict__ W2,
                                               float* __restrict__ xlp){
    __shared__ __align__(16) float as[KC][68];
    __shared__ __align__(16) float ws[KC][128];
    int bid = blockIdx.x;
    int ks = bid & (KS - 1);
    int r0 = (bid >> 2) * 64;
    int t = threadIdx.x;
    int rg = t >> 5, jq = t & 31;
    float acc[8][4];
#pragma unroll
    for (int i = 0; i < 8; ++i)
#pragma unroll
        for (int j = 0; j < 4; ++j) acc[i][j] = 0.f;
    for (int kc = ks*KSEG; kc < ks*KSEG + KSEG; kc += KC){
        for (int i = t; i < 64*KC; i += 256){
            int r = i / KC, k = i % KC;
            as[k][r] = h1[(size_t)(r0 + r)*D1 + kc + k];
        }
        for (int i = t; i < KC*128; i += 256){
            int k = i >> 7, j = i & 127;
            ws[k][j] = W2[(size_t)(kc + k)*OD + j];
        }
        __syncthreads();
        for (int k = 0; k < KC; ++k){
            float4 a0 = *(const float4*)&as[k][rg*8];
            float4 a1 = *(const float4*)&as[k][rg*8 + 4];
            float4 w4 = *(const float4*)&ws[k][jq*4];
            float av[8] = {a0.x, a0.y, a0.z, a0.w, a1.x, a1.y, a1.z, a1.w};
            float wv[4] = {w4.x, w4.y, w4.z, w4.w};
#pragma unroll
            for (int i = 0; i < 8; ++i)
#pragma unroll
                for (int j = 0; j < 4; ++j) acc[i][j] += av[i]*wv[j];
        }
        __syncthreads();
    }
    float* dst = xlp + (size_t)ks*NN*OD;
#pragma unroll
    for (int i = 0; i < 8; ++i){
        float4 o4 = make_float4(acc[i][0], acc[i][1], acc[i][2], acc[i][3]);
        *(float4*)&dst[(size_t)(r0 + rg*8 + i)*OD + jq*4] = o4;
    }
}

// reduce 4 partials -> xl2, fused alpha2
__global__ __launch_bounds__(128) void k_red(const float* __restrict__ xlp,
                                             const float* __restrict__ s2w, const float* __restrict__ d2w,
                                             float* __restrict__ xl2,
                                             float* __restrict__ as2, float* __restrict__ ad2){
    const size_t Q = (size_t)NN*OD/4;
    int t = threadIdx.x;
    size_t fi = (size_t)blockIdx.x*128 + t;
    const float4* P = (const float4*)xlp;
    float4 a = P[fi], b = P[fi + Q], c = P[fi + 2*Q], d = P[fi + 3*Q];
    float4 v = make_float4(a.x+b.x+c.x+d.x, a.y+b.y+c.y+d.y,
                           a.z+b.z+c.z+d.z, a.w+b.w+c.w+d.w);
    ((float4*)xl2)[fi] = v;
    int cc = (t & 31)*4;
    float sa = v.x*s2w[cc] + v.y*s2w[cc+1] + v.z*s2w[cc+2] + v.w*s2w[cc+3];
    float sd = v.x*d2w[cc] + v.y*d2w[cc+1] + v.z*d2w[cc+2] + v.w*d2w[cc+3];
#pragma unroll
    for (int o = 16; o; o >>= 1){ sa += __shfl_xor(sa, o); sd += __shfl_xor(sd, o); }
    if ((t & 31) == 0){
        int n = blockIdx.x*4 + (t >> 5);
        as2[n] = sa; ad2[n] = sd;
    }
}

// per dst: lane-owned alpha, chunk-register staged gather
__global__ __launch_bounds__(64) void k_gat2(const float* __restrict__ xl2, const float* __restrict__ as2,
                                             const float* __restrict__ ad2, const int* __restrict__ off,
                                             const int* __restrict__ csrc, const float* __restrict__ b2,
                                             float* __restrict__ h2){
    int dst = blockIdx.x, lane = threadIdx.x;
    int beg = off[dst], end = off[dst + 1];
    int deg = end - beg;
    float ad = ad2[dst];
    int s0 = 0; float v0 = -1e30f;
    if (lane < deg){
        s0 = csrc[beg + lane];
        float v = as2[s0] + ad;
        v0 = v > 0.f ? v : SLOPE*v;
    }
    float m = v0;
    if (deg > 64){
        for (int e = beg + 64 + lane; e < end; e += 64){
            float v = as2[csrc[e]] + ad; v = v > 0.f ? v : SLOPE*v;
            m = fmaxf(m, v);
        }
    }
    for (int o = 32; o; o >>= 1) m = fmaxf(m, __shfl_xor(m, o));
    float pe = (lane < deg) ? __expf(v0 - m) : 0.f;
    float sm = pe;
    if (deg > 64){
        for (int e = beg + 64 + lane; e < end; e += 64){
            float v = as2[csrc[e]] + ad; v = v > 0.f ? v : SLOPE*v;
            sm += __expf(v - m);
        }
    }
    for (int o = 32; o; o >>= 1) sm += __shfl_xor(sm, o);
    float inv = 1.f / (sm + 1e-16f);
    float p = pe * inv;
    float a0 = 0.f, a1 = 0.f;
    int cnt0 = deg < 64 ? deg : 64;
    for (int c0 = 0; c0 < cnt0; c0 += 16){
        float r1[16], r2[16];
#pragma unroll
        for (int i = 0; i < 16; ++i){            // 32 independent loads in flight
            int s = __shfl(s0, c0 + i);
            r1[i] = xl2[(size_t)s*OD + lane];
            r2[i] = xl2[(size_t)s*OD + 64 + lane];
        }
#pragma unroll
        for (int i = 0; i < 16; ++i){
            if (c0 + i < cnt0){
                float al = __shfl(p, c0 + i);
                a0 += al*r1[i];
                a1 += al*r2[i];
            }
        }
    }
    if (deg > 64){
        for (int base = beg + 64; base < end; base += 64){
            int cnt = min(64, end - base);
            int s1 = 0; float pp = 0.f;
            if (lane < cnt){
                s1 = csrc[base + lane];
                float v = as2[s1] + ad; v = v > 0.f ? v : SLOPE*v;
                pp = __expf(v - m) * inv;
            }
            for (int c0 = 0; c0 < cnt; c0 += 16){
                float r1[16], r2[16];
#pragma unroll
                for (int i = 0; i < 16; ++i){
                    int s = __shfl(s1, c0 + i);
                    r1[i] = xl2[(size_t)s*OD + lane];
                    r2[i] = xl2[(size_t)s*OD + 64 + lane];
                }
#pragma unroll
                for (int i = 0; i < 16; ++i){
                    if (c0 + i < cnt){
                        float al = __shfl(pp, c0 + i);
                        a0 += al*r1[i];
                        a1 += al*r2[i];
                    }
                }
            }
        }
    }
    float o0 = a0 + b2[lane];      o0 = o0 > 0.f ? o0 : 0.f;
    float o1 = a1 + b2[64 + lane]; o1 = o1 > 0.f ? o1 : 0.f;
    h2[(size_t)dst*OD + lane] = o0;
    h2[(size_t)dst*OD + 64 + lane] = o1;
}

// ---------------- pooling + graph FC (fused) ----------------
__global__ __launch_bounds__(128) void k_poolfc(const float* __restrict__ h2, const int* __restrict__ batch,
                                                const float* __restrict__ w, const float* __restrict__ bias,
                                                float* __restrict__ gfc){
    __shared__ float row[OD];
    int b = blockIdx.x, t = threadIdx.x;
    int lo = 0, hi = NN;
    while (lo < hi){ int mid = (lo + hi) >> 1; if (batch[mid] < b) lo = mid + 1; else hi = mid; }
    int s0 = lo;
    lo = s0; hi = NN;
    while (lo < hi){ int mid = (lo + hi) >> 1; if (batch[mid] < b + 1) lo = mid + 1; else hi = mid; }
    int s1 = lo;
    float mx = 0.f;
    for (int n = s0; n < s1; ++n) mx = fmaxf(mx, h2[(size_t)n*OD + t]);
    row[t] = mx;
    __syncthreads();
    float acc = 0.f;
    for (int k = 0; k < OD; ++k) acc += row[k] * w[k*OD + t];
    acc += bias[t];
    gfc[b*OD + t] = acc > 0.f ? acc : 0.f;
}

// ---------------- protein branch ----------------
__global__ __launch_bounds__(256) void k_wt(const float* __restrict__ convw, float* __restrict__ wt){
    int idx = blockIdx.x*256 + threadIdx.x;
    int i = idx >> 8, ok = idx & 255;
    wt[idx] = convw[(size_t)(ok >> 3)*PL*8 + (size_t)i*8 + (ok & 7)];
}

// A-partials per (b, seg): fixed-point + native integer LDS atomics (ds_add_u32)
__global__ __launch_bounds__(256) void k_abuild(const int* __restrict__ target, const float* __restrict__ wt,
                                                float* __restrict__ Ag){
    __shared__ int Ai[VOC][256];
    __shared__ int tss[256];
    int b = blockIdx.x >> 2, seg = blockIdx.x & 3;
    int t = threadIdx.x;
#pragma unroll
    for (int v = 0; v < VOC; ++v) Ai[v][t] = 0;
    if (t < 250) tss[t] = target[b*PL + seg*250 + t];
    __syncthreads();
    const float* wtb = wt + (size_t)(seg*250)*256 + t;
    const float SC = 16777216.0f;               // 2^24
    for (int i = 0; i < 250; ++i){
        float w = wtb[(size_t)i*256];
        int q = __float2int_rn(w * SC);
        atomicAdd(&Ai[tss[i]][t], q);
    }
    __syncthreads();
    const float INV = 5.9604644775390625e-08f;  // 2^-24
    float* Ao = Ag + (size_t)blockIdx.x*VOC*256 + t;
#pragma unroll
    for (int v = 0; v < VOC; ++v) Ao[(size_t)v*256] = (float)Ai[v][t] * INV;
}

__global__ __launch_bounds__(256) void k_conv(const float* __restrict__ Ag, const float* __restrict__ emb,
                                              const float* __restrict__ convb, float* __restrict__ cbuf){
    __shared__ float As[VOC][128];
    __shared__ float embs[VOC*128 + 16];
    int b = blockIdx.x >> 1, half = blockIdx.x & 1;
    int t = threadIdx.x;
    for (int i = t; i < VOC*128; i += 256){
        int v = i >> 7, c = i & 127;
        float s = 0.f;
#pragma unroll
        for (int seg = 0; seg < 4; ++seg)
            s += Ag[((size_t)(b*4 + seg)*VOC + v)*256 + half*128 + c];
        As[v][c] = s;
        embs[i] = emb[i];
    }
    if (t < 16) embs[VOC*128 + t] = 0.f;
    __syncthreads();
    int o_l = t >> 4, pg = t & 15, p0 = pg * 8;
    float accp[8];
#pragma unroll
    for (int i = 0; i < 8; ++i) accp[i] = 0.f;
    for (int v = 0; v < VOC; ++v){
        float w[15];
        const float* er = embs + v*128 + p0;
#pragma unroll
        for (int i = 0; i < 15; ++i) w[i] = er[i];
#pragma unroll
        for (int k2 = 0; k2 < 8; ++k2){
            float a = As[v][o_l*8 + k2];
#pragma unroll
            for (int j = 0; j < 8; ++j) accp[j] += a * w[j + k2];
        }
    }
    float cbv = convb[half*16 + o_l];
#pragma unroll
    for (int j = 0; j < 8; ++j){
        int p = p0 + j;
        if (p < 121){
            float v2 = accp[j] + cbv;
            cbuf[(size_t)b*3872 + (half*16 + o_l)*121 + p] = v2 > 0.f ? v2 : 0.f;
        }
    }
}

__global__ __launch_bounds__(256) void k_xt(const float* __restrict__ cbuf, const float* __restrict__ fxw,
                                            float* __restrict__ xtp){
    __shared__ float csh[16][242];
    int kt = blockIdx.x >> 3, bt = blockIdx.x & 7;
    int t = threadIdx.x;
    for (int i = t; i < 16*242; i += 256){
        int bb = i / 242, kk = i % 242;
        csh[bb][kk] = cbuf[(size_t)(bt*16 + bb)*3872 + kt*242 + kk];
    }
    __syncthreads();
    int j = t & 127, bh = t >> 7;
    float acc[8];
#pragma unroll
    for (int i = 0; i < 8; ++i) acc[i] = 0.f;
    for (int kk = 0; kk < 242; ++kk){
        float w = fxw[(size_t)(kt*242 + kk)*128 + j];
#pragma unroll
        for (int bb = 0; bb < 8; ++bb) acc[bb] += csh[bh*8 + bb][kk] * w;
    }
#pragma unroll
    for (int bb = 0; bb < 8; ++bb)
        xtp[(size_t)kt*NB*128 + (size_t)(bt*16 + bh*8 + bb)*128 + j] = acc[bb];
}

// ---------------- fused head ----------------
__global__ __launch_bounds__(256) void k_fc1(const float* __restrict__ gfc, const float* __restrict__ xtp,
                                             const float* __restrict__ fxb,
                                             const float* __restrict__ w, const float* __restrict__ bias,
                                             float* __restrict__ out){
    __shared__ float xc[256];
    int b = blockIdx.x, t = threadIdx.x;
    if (t < 128) xc[t] = gfc[b*OD + t];
    else {
        int j = t - 128;
        float s = fxb[j];
#pragma unroll
        for (int kt = 0; kt < 16; ++kt) s += xtp[(size_t)kt*NB*128 + (size_t)b*128 + j];
        xc[t] = s;
    }
    __syncthreads();
#pragma unroll
    for (int rep = 0; rep < 4; ++rep){
        int j = t + rep*256;
        float acc = 0.f;
        for (int k = 0; k < 256; ++k) acc += xc[k] * w[(size_t)k*1024 + j];
        acc += bias[j];
        out[b*1024 + j] = acc > 0.f ? acc : 0.f;
    }
}

__global__ __launch_bounds__(256) void k_fc2o(const float* __restrict__ in, const float* __restrict__ w,
                                              const float* __restrict__ bias, const float* __restrict__ ow,
                                              const float* __restrict__ ob, float* __restrict__ out){
    __shared__ float row[1024];
    __shared__ float s2[256];
    int b = blockIdx.x, t = threadIdx.x;
    for (int i = t; i < 1024; i += 256) row[i] = in[b*1024 + i];
    __syncthreads();
    float acc = 0.f;
    for (int k = 0; k < 1024; ++k) acc += row[k] * w[(size_t)k*256 + t];
    acc += bias[t];
    acc = acc > 0.f ? acc : 0.f;
    s2[t] = acc * ow[t];
    __syncthreads();
    if (t < 64){
        float a = s2[t] + s2[t + 64] + s2[t + 128] + s2[t + 192];
#pragma unroll
        for (int o = 32; o; o >>= 1) a += __shfl_xor(a, o);
        if (t == 0) out[b] = a + ob[0];
    }
}

extern "C" void kernel_launch(void* const* d_in, const int* in_sizes, int n_in,
                              void* d_out, int out_size, void* d_ws, size_t ws_size,
                              hipStream_t stream){
    const float* x    = (const float*)d_in[0];
    const int*  ei    = (const int*)d_in[1];
    const int*  batch = (const int*)d_in[2];
    const int*  target= (const int*)d_in[3];
    const float* W1   = (const float*)d_in[4];
    const float* as1w = (const float*)d_in[5];
    const float* ad1w = (const float*)d_in[6];
    const float* b1   = (const float*)d_in[7];
    const float* W2   = (const float*)d_in[8];
    const float* as2w = (const float*)d_in[9];
    const float* ad2w = (const float*)d_in[10];
    const float* b2   = (const float*)d_in[11];
    const float* fgw  = (const float*)d_in[12];
    const float* fgb  = (const float*)d_in[13];
    const float* emb  = (const float*)d_in[14];
    const float* cw   = (const float*)d_in[15];
    const float* cb   = (const float*)d_in[16];
    const float* fxw  = (const float*)d_in[17];
    const float* fxb  = (const float*)d_in[18];
    const float* f1w  = (const float*)d_in[19];
    const float* f1b  = (const float*)d_in[20];
    const float* f2w  = (const float*)d_in[21];
    const float* f2b  = (const float*)d_in[22];
    const float* ow   = (const float*)d_in[23];
    const float* ob   = (const float*)d_in[24];

    float* f = (float*)d_ws;
    size_t o = 0;
    float* agg = f + o; o += (size_t)NN*D1;     // reused as xlp (4*NN*OD <= NN*D1)
    float* h1  = f + o; o += (size_t)NN*D1;     // reused as Ag after k_gemm2
    float* as1 = f + o; o += (size_t)NN*HEADS;
    float* ad1 = f + o; o += (size_t)NN*HEADS;
    float* xl2 = f + o; o += (size_t)NN*OD;
    float* h2  = f + o; o += (size_t)NN*OD;
    float* as2 = f + o; o += NN;
    float* ad2 = f + o; o += NN;
    float* gfc = f + o; o += NB*OD;
    float* hf1 = f + o; o += NB*1024;
    float* vas = f + o; o += D1;
    float* vad = f + o; o += D1;
    float* wt  = f + o; o += (size_t)PL*256;
    float* cbuf= f + o; o += (size_t)NB*3872;
    float* xtp = f + o; o += (size_t)16*NB*128;
    int* cnt   = (int*)(f + o); o += NN;
    int* off   = (int*)(f + o); o += NN + 1;
    int* csrc  = (int*)(f + o); o += ET;
    float* xlp = agg;   // agg dead after k_post1
    float* Ag  = h1;    // h1 dead after k_gemm2; abuild launches after k_poolfc
    (void)ws_size; (void)in_sizes; (void)n_in; (void)out_size;

    // CSR by destination
    hipMemsetAsync(cnt, 0, NN*sizeof(int), stream);
    k_hist<<<(ET + 255)/256, 256, 0, stream>>>(ei, cnt);
    k_scan<<<1, 1024, 0, stream>>>(cnt, off);
    hipMemsetAsync(cnt, 0, NN*sizeof(int), stream);
    k_fill<<<(ET + 255)/256, 256, 0, stream>>>(ei, off, cnt, csrc);

    // GAT layer 1 in x-space
    k_va<<<1, 256, 0, stream>>>(W1, as1w, ad1w, vas, vad);
    k_alpha1x<<<NN/64, 256, 0, stream>>>(x, vas, vad, as1, ad1);
    k_gat1x<<<NN, 64, 0, stream>>>(x, as1, ad1, off, csrc, agg);
    k_post1<<<HEADS*256, 256, 0, stream>>>(agg, W1, b1, h1);

    // GAT layer 2 (K-split GEMM + fused reduce/alpha2)
    k_gemm2<<<(NN/64)*KS, 256, 0, stream>>>(h1, W2, xlp);
    k_red<<<NN/4, 128, 0, stream>>>(xlp, as2w, ad2w, xl2, as2, ad2);
    k_gat2<<<NN, 64, 0, stream>>>(xl2, as2, ad2, off, csrc, b2, h2);

    // pooling + graph fc (fused)
    k_poolfc<<<NB, 128, 0, stream>>>(h2, batch, fgw, fgb, gfc);

    // protein branch
    k_wt<<<1000, 256, 0, stream>>>(cw, wt);
    k_abuild<<<NB*4, 256, 0, stream>>>(target, wt, Ag);
    k_conv<<<NB*2, 256, 0, stream>>>(Ag, emb, cb, cbuf);
    k_xt<<<128, 256, 0, stream>>>(cbuf, fxw, xtp);

    // head
    k_fc1<<<NB, 256, 0, stream>>>(gfc, xtp, fxb, f1w, f1b, hf1);
    k_fc2o<<<NB, 256, 0, stream>>>(hf1, f2w, f2b, ow, ob, (float*)d_out);
}